// Round 13
// baseline (736.710 us; speedup 1.0000x reference)
//
#include <hip/hip_runtime.h>
#include <hip/hip_bf16.h>

#define B_   2
#define C_   64
#define H_   48
#define W_   48
#define N_   (H_*W_)     // 2304
#define NH_  8
#define HD_  8
#define EPS_ 1e-5f
#define S2_  0.125f      // scale^2 = 1/hd
#define LOG2E_ 1.44269504f
#define S_   ((size_t)B_ * C_ * N_)   // 294912 floats per workspace slot
#define CN_  ((size_t)C_ * N_)        // 147456 floats per image

__device__ __forceinline__ float wsum64(float v) {
#pragma unroll
  for (int o = 32; o > 0; o >>= 1) v += __shfl_xor(v, o, 64);
  return v;
}

__device__ __forceinline__ float ln_val(float t, float g, float b) {
  float mu  = wsum64(t) * (1.0f / 64.0f);
  float d   = t - mu;
  float var = wsum64(d * d) * (1.0f / 64.0f);
  return d * rsqrtf(var + EPS_) * g + b;
}

// ---- fused 1x1 pconv + BN + 3x LayerNorm; block = one (b,n) row ----------
__global__ __launch_bounds__(64) void k_pre(
    const float* __restrict__ x, const float* __restrict__ y,
    const float* __restrict__ pw, const float* __restrict__ pb,
    const float* g, const float* bb, const float* m, const float* v,
    const float* lnxg, const float* lnxb,
    const float* lnyg, const float* lnyb,
    const float* lnzg, const float* lnzb,
    float* __restrict__ xl, float* __restrict__ yl, float* __restrict__ zl) {
  __shared__ float xs[64], ys[64];
  int row = blockIdx.x;            // b*N + n
  int c = threadIdx.x;
  int b = row / N_, n = row % N_;
  float xv = x[(size_t)(b * C_ + c) * N_ + n];
  float yv = y[(size_t)(b * C_ + c) * N_ + n];
  xs[c] = xv; ys[c] = yv;
  __syncthreads();
  const float4* wr  = (const float4*)(pw + (size_t)c * 2 * C_);
  const float4* xs4 = (const float4*)xs;
  const float4* ys4 = (const float4*)ys;
  float acc = pb[c];
#pragma unroll
  for (int t = 0; t < 16; ++t) {
    float4 a = xs4[t], wv = wr[t];
    acc += a.x * wv.x + a.y * wv.y + a.z * wv.z + a.w * wv.w;
  }
#pragma unroll
  for (int t = 0; t < 16; ++t) {
    float4 a = ys4[t], wv = wr[16 + t];
    acc += a.x * wv.x + a.y * wv.y + a.z * wv.z + a.w * wv.w;
  }
  float s  = g[c] * rsqrtf(v[c] + EPS_);
  float sh = bb[c] - m[c] * s;
  float tx = xv * s + sh;
  xl[(size_t)row * C_ + c] = ln_val(tx, lnxg[c], lnxb[c]);
  float ty = yv * s + sh;
  yl[(size_t)row * C_ + c] = ln_val(ty, lnyg[c], lnyb[c]);
  float tz = acc * s + sh;
  zl[(size_t)row * C_ + c] = ln_val(tz, lnzg[c], lnzb[c]);
}

// ------------- fused qv (both branches) + k projection --------------------
__global__ void k_qvk(const float* __restrict__ lnb, const float* __restrict__ zl,
                      const float* __restrict__ qvw, const float* __restrict__ qvb,
                      const float* __restrict__ kw, const float* __restrict__ kb,
                      float* __restrict__ qb, float* __restrict__ vb,
                      float* __restrict__ kk) {
  int z = blockIdx.z;
  if (z < 2) {
    int idx = blockIdx.x * 256 + threadIdx.x;   // B*N*128
    int j = idx & 127;
    int row = idx >> 7;
    int b = row / N_, n = row % N_;
    const float4* ir = (const float4*)(lnb + z * S_ + (size_t)row * C_);
    const float4* wr = (const float4*)(qvw + (size_t)j * C_);
    float acc = qvb[j];
#pragma unroll
    for (int t = 0; t < 16; ++t) {
      float4 a = ir[t], wv = wr[t];
      acc += a.x * wv.x + a.y * wv.y + a.z * wv.z + a.w * wv.w;
    }
    int jj = j & 63;
    int h = jj >> 3, d = jj & 7;
    float* dst = ((j < C_) ? qb : vb) + z * 2 * S_;
    dst[((size_t)(b * NH_ + h) * N_ + n) * HD_ + d] = acc;
  } else {
    if (blockIdx.x >= 1152) return;
    int idx = blockIdx.x * 256 + threadIdx.x;   // B*N*64
    int j = idx & 63;
    int row = idx >> 6;
    int b = row / N_, n = row % N_;
    const float4* ir = (const float4*)(zl + (size_t)row * C_);
    const float4* wr = (const float4*)(kw + (size_t)j * C_);
    float acc = kb[j];
#pragma unroll
    for (int t = 0; t < 16; ++t) {
      float4 a = ir[t], wv = wr[t];
      acc += a.x * wv.x + a.y * wv.y + a.z * wv.z + a.w * wv.w;
    }
    int h = j >> 3, d = j & 7;
    kk[((size_t)(b * NH_ + h) * N_ + n) * HD_ + d] = acc;
  }
}

// ---------------- attention v7: 16 waves, no-max, 2-key ILP ---------------
#define AW 16
__global__ __launch_bounds__(1024, 8) void k_attn7(
    const float* __restrict__ xq, const float* __restrict__ xv,
    const float* __restrict__ yq, const float* __restrict__ yv,
    const float* __restrict__ kk,
    float* __restrict__ outx, float* __restrict__ outy) {
  __shared__ float pl[AW][64];
  __shared__ float pbuf[AW][8][64];
  int bh  = blockIdx.y;
  int qt  = blockIdx.x;
  int tid = threadIdx.x;
  int lane = tid & 63;
  int wave = __builtin_amdgcn_readfirstlane(tid >> 6);
  int q = qt * 64 + lane;
  size_t base = (size_t)bh * N_ * HD_;

  float4 qx0 = ((const float4*)(xq + base + (size_t)q * HD_))[0];
  float4 qx1 = ((const float4*)(xq + base + (size_t)q * HD_))[1];
  float4 qy0 = ((const float4*)(yq + base + (size_t)q * HD_))[0];
  float4 qy1 = ((const float4*)(yq + base + (size_t)q * HD_))[1];
  const float fs = S2_ * LOG2E_;
  qx0.x *= fs; qx0.y *= fs; qx0.z *= fs; qx0.w *= fs;
  qx1.x *= fs; qx1.y *= fs; qx1.z *= fs; qx1.w *= fs;

  float l = 0.f;
  float ax[8] = {0,0,0,0,0,0,0,0};
  float ay[8] = {0,0,0,0,0,0,0,0};

  const float4* kp = (const float4*)(kk + base);
  const float4* xp = (const float4*)(xv + base);
  const float4* yp = (const float4*)(yv + base);
  int k0 = wave * (N_ / AW);
  for (int mi = k0; mi < k0 + N_ / AW; mi += 2) {
    float4 kaA  = kp[2 * mi],     kbA = kp[2 * mi + 1];
    float4 kaB  = kp[2 * mi + 2], kbB = kp[2 * mi + 3];
    float4 xaA = xp[2 * mi],     xbA = xp[2 * mi + 1];
    float4 xaB = xp[2 * mi + 2], xbB = xp[2 * mi + 3];
    float4 yaA = yp[2 * mi],     ybA = yp[2 * mi + 1];
    float4 yaB = yp[2 * mi + 2], ybB = yp[2 * mi + 3];
    float s1A = qx0.x*kaA.x + qx0.y*kaA.y + qx0.z*kaA.z + qx0.w*kaA.w
              + qx1.x*kbA.x + qx1.y*kbA.y + qx1.z*kbA.z + qx1.w*kbA.w;
    float s2A = qy0.x*kaA.x + qy0.y*kaA.y + qy0.z*kaA.z + qy0.w*kaA.w
              + qy1.x*kbA.x + qy1.y*kbA.y + qy1.z*kbA.z + qy1.w*kbA.w;
    float s1B = qx0.x*kaB.x + qx0.y*kaB.y + qx0.z*kaB.z + qx0.w*kaB.w
              + qx1.x*kbB.x + qx1.y*kbB.y + qx1.z*kbB.z + qx1.w*kbB.w;
    float s2B = qy0.x*kaB.x + qy0.y*kaB.y + qy0.z*kaB.z + qy0.w*kaB.w
              + qy1.x*kbB.x + qy1.y*kbB.y + qy1.z*kbB.z + qy1.w*kbB.w;
    float pA = exp2f(s1A * s2A);
    float pB = exp2f(s1B * s2B);
    l += pA + pB;
    ax[0] += pA*xaA.x + pB*xaB.x;  ax[1] += pA*xaA.y + pB*xaB.y;
    ax[2] += pA*xaA.z + pB*xaB.z;  ax[3] += pA*xaA.w + pB*xaB.w;
    ax[4] += pA*xbA.x + pB*xbB.x;  ax[5] += pA*xbA.y + pB*xbB.y;
    ax[6] += pA*xbA.z + pB*xbB.z;  ax[7] += pA*xbA.w + pB*xbB.w;
    ay[0] += pA*yaA.x + pB*yaB.x;  ay[1] += pA*yaA.y + pB*yaB.y;
    ay[2] += pA*yaA.z + pB*yaB.z;  ay[3] += pA*yaA.w + pB*yaB.w;
    ay[4] += pA*ybA.x + pB*ybB.x;  ay[5] += pA*ybA.y + pB*ybB.y;
    ay[6] += pA*ybA.z + pB*ybB.z;  ay[7] += pA*ybA.w + pB*ybB.w;
  }
  pl[wave][lane] = l;
#pragma unroll
  for (int d = 0; d < 8; ++d) pbuf[wave][d][lane] = ax[d];
  __syncthreads();
  float Linv = 0.f;
  int b = bh / NH_, h = bh % NH_;
  if (tid < 64) {
    float L = 0.f;
#pragma unroll
    for (int w = 0; w < AW; ++w) L += pl[w][lane];
    Linv = 1.f / L;
    float A[8] = {0,0,0,0,0,0,0,0};
#pragma unroll
    for (int w = 0; w < AW; ++w)
#pragma unroll
      for (int d = 0; d < 8; ++d) A[d] += pbuf[w][d][lane];
    float* o = outx + ((size_t)(b * N_ + q)) * C_ + h * HD_;
#pragma unroll
    for (int d = 0; d < 8; ++d) o[d] = A[d] * Linv;
  }
  __syncthreads();
#pragma unroll
  for (int d = 0; d < 8; ++d) pbuf[wave][d][lane] = ay[d];
  __syncthreads();
  if (tid < 64) {
    float A[8] = {0,0,0,0,0,0,0,0};
#pragma unroll
    for (int w = 0; w < AW; ++w)
#pragma unroll
      for (int d = 0; d < 8; ++d) A[d] += pbuf[w][d][lane];
    float* o = outy + ((size_t)(b * N_ + q)) * C_ + h * HD_;
#pragma unroll
    for (int d = 0; d < 8; ++d) o[d] = A[d] * Linv;
  }
}

// -------- proj + recomputed-BN residual, 2 px/thread ----------------------
// grid (18, C_, 2*B_), block 64. out layout z*CN, z = branch*B_ + b.
__global__ __launch_bounds__(64) void k_proj2(
    const float* __restrict__ attbase,
    const float* __restrict__ x, const float* __restrict__ y,
    const float* bg, const float* bb2, const float* bm, const float* bv,
    const float* __restrict__ pw, const float* __restrict__ pbias,
    float* __restrict__ outbase) {
  int p = blockIdx.x * 128 + threadIdx.x * 2;
  int c = blockIdx.y;
  int z = blockIdx.z;
  int branch = z >> 1, b = z & 1;
  const float* att = attbase + branch * S_ + (size_t)b * N_ * C_;
  const float4* wr = (const float4*)(pw + (size_t)c * C_);
  float bias = pbias[c];
  float acc[2];
#pragma unroll
  for (int i = 0; i < 2; ++i) {
    const float4* ar = (const float4*)(att + (size_t)(p + i) * C_);
    float a = bias;
#pragma unroll
    for (int t = 0; t < 16; ++t) {
      float4 av = ar[t], wv = wr[t];
      a += av.x * wv.x + av.y * wv.y + av.z * wv.z + av.w * wv.w;
    }
    acc[i] = a;
  }
  float s  = bg[c] * rsqrtf(bv[c] + EPS_);
  float sh = bb2[c] - bm[c] * s;
  const float* xin = branch ? y : x;
  float2 r = *(const float2*)(xin + ((size_t)b * C_ + c) * N_ + p);
  size_t o = (size_t)z * CN_ + (size_t)c * N_ + p;
  *(float2*)(outbase + o) = make_float2(acc[0] + r.x * s + sh,
                                        acc[1] + r.y * s + sh);
}

// ------ conv1: one image per z, 2 couts, 1 px/thread ----------------------
// grid (36, C_/2, 2*B_), block 64. z = branch*B_ + b (layout z*CN).
__global__ __launch_bounds__(64) void k_convp(
    const float* __restrict__ in, const float* __restrict__ w,
    const float* __restrict__ cb,
    const float* __restrict__ bg, const float* __restrict__ bbeta,
    const float* __restrict__ bm, const float* __restrict__ bv,
    float* __restrict__ out) {
  int p = blockIdx.x * 64 + threadIdx.x;
  int c0 = blockIdx.y * 2;
  int z = blockIdx.z;
  int yy = p / W_, x0 = p % W_;
  const float* ib = in + (size_t)z * CN_;
  const float* w0r = w + (size_t)c0 * C_ * 9;
  const float* w1r = w0r + (size_t)C_ * 9;
  float a0 = cb[c0], a1 = cb[c0 + 1];
#pragma unroll 2
  for (int ci = 0; ci < C_; ++ci) {
    const float* ip = ib + ci * N_;
    const float* wp0 = w0r + ci * 9;
    const float* wp1 = w1r + ci * 9;
#pragma unroll
    for (int ky = 0; ky < 3; ++ky) {
      int iyy = yy + ky - 1;
      if ((unsigned)iyy >= (unsigned)H_) continue;
      const float* rp = ip + iyy * W_;
      float vm = rp[x0];
      float vL = (x0 > 0)      ? rp[x0 - 1] : 0.f;
      float vR = (x0 + 1 < W_) ? rp[x0 + 1] : 0.f;
      a0 += vL * wp0[ky*3] + vm * wp0[ky*3+1] + vR * wp0[ky*3+2];
      a1 += vL * wp1[ky*3] + vm * wp1[ky*3+1] + vR * wp1[ky*3+2];
    }
  }
  float s0 = bg[c0] * rsqrtf(bv[c0] + EPS_);
  float sh0 = bbeta[c0] - bm[c0] * s0;
  float s1 = bg[c0+1] * rsqrtf(bv[c0+1] + EPS_);
  float sh1 = bbeta[c0+1] - bm[c0+1] * s1;
  size_t o = (size_t)z * CN_ + (size_t)c0 * N_ + p;
  out[o]      = fmaxf(a0 * s0 + sh0, 0.f);
  out[o + N_] = fmaxf(a1 * s1 + sh1, 0.f);
}

// ------ conv2 + bn + relu + resid, one image per z, 1 px/thread -----------
// grid (36, C_/2, 2*B_), block 64. in/resid/out layout z*CN.
__global__ __launch_bounds__(64) void k_conv2b(
    const float* __restrict__ in, const float* __restrict__ w,
    const float* __restrict__ cb,
    const float* __restrict__ bg, const float* __restrict__ bbeta,
    const float* __restrict__ bm, const float* __restrict__ bv,
    const float* __restrict__ resid, float* __restrict__ out) {
  int p = blockIdx.x * 64 + threadIdx.x;
  int c0 = blockIdx.y * 2;
  int z = blockIdx.z;
  int yy = p / W_, x0 = p % W_;
  const float* ib = in + (size_t)z * CN_;
  const float* w0r = w + (size_t)c0 * C_ * 9;
  const float* w1r = w0r + (size_t)C_ * 9;
  float a0 = cb[c0], a1 = cb[c0 + 1];
#pragma unroll 2
  for (int ci = 0; ci < C_; ++ci) {
    const float* ip = ib + ci * N_;
    const float* wp0 = w0r + ci * 9;
    const float* wp1 = w1r + ci * 9;
#pragma unroll
    for (int ky = 0; ky < 3; ++ky) {
      int iyy = yy + ky - 1;
      if ((unsigned)iyy >= (unsigned)H_) continue;
      const float* rp = ip + iyy * W_;
      float vm = rp[x0];
      float vL = (x0 > 0)      ? rp[x0 - 1] : 0.f;
      float vR = (x0 + 1 < W_) ? rp[x0 + 1] : 0.f;
      a0 += vL * wp0[ky*3] + vm * wp0[ky*3+1] + vR * wp0[ky*3+2];
      a1 += vL * wp1[ky*3] + vm * wp1[ky*3+1] + vR * wp1[ky*3+2];
    }
  }
  float s0 = bg[c0] * rsqrtf(bv[c0] + EPS_);
  float sh0 = bbeta[c0] - bm[c0] * s0;
  float s1 = bg[c0+1] * rsqrtf(bv[c0+1] + EPS_);
  float sh1 = bbeta[c0+1] - bm[c0+1] * s1;
  size_t o = (size_t)z * CN_ + (size_t)c0 * N_ + p;
  out[o]      = fmaxf(a0 * s0 + sh0, 0.f) + resid[o];
  out[o + N_] = fmaxf(a1 * s1 + sh1, 0.f) + resid[o + N_];
}

// ------ cat = [xo+yo ; xo*yo] + bn2 -> fin, float4 ------------------------
// grid 576, block 256. o2 layout z*CN (z=branch*B+b). fin b at fin+b*finStride.
__global__ void k_catbn(const float* __restrict__ o2,
                        const float* __restrict__ g, const float* __restrict__ b2,
                        const float* __restrict__ m, const float* __restrict__ v,
                        float* __restrict__ cat, float* __restrict__ fin,
                        size_t finStride) {
  int t = blockIdx.x * 256 + threadIdx.x;
  int p4 = t * 4;
  int n  = p4 % N_;
  int c2 = (p4 / N_) % (2 * C_);
  int b  = p4 / (2 * C_ * N_);
  int c  = c2 & 63;
  float4 X = *(const float4*)(o2 + (size_t)b * CN_ + (size_t)c * N_ + n);
  float4 Y = *(const float4*)(o2 + (size_t)(2 + b) * CN_ + (size_t)c * N_ + n);
  float4 val;
  if (c2 < C_) val = make_float4(X.x + Y.x, X.y + Y.y, X.z + Y.z, X.w + Y.w);
  else         val = make_float4(X.x * Y.x, X.y * Y.y, X.z * Y.z, X.w * Y.w);
  size_t co = ((size_t)b * 2 * C_ + c2) * N_ + n;
  *(float4*)(cat + co) = val;
  float s  = g[c2] * rsqrtf(v[c2] + EPS_);
  float sh = b2[c2] - m[c2] * s;
  *(float4*)(fin + (size_t)b * finStride + (size_t)c2 * N_ + n) =
      make_float4(val.x * s + sh, val.y * s + sh, val.z * s + sh, val.w * s + sh);
}

// ------ f-branch 3x3 conv partial (64-cin half), 2 couts, 1 px/thread -----
// grid (36, C_, 2*B_), block 64. z: b = z&1, half = z>>1.
__global__ __launch_bounds__(64) void k_fconvs(
    const float* __restrict__ in, size_t inStride,
    const float* __restrict__ w,
    float* __restrict__ outA, size_t outStrideA,
    float* __restrict__ outB, size_t outStrideB) {
  int p = blockIdx.x * 64 + threadIdx.x;
  int c0 = blockIdx.y * 2;
  int z = blockIdx.z;
  int b = z & 1, half = z >> 1;
  int yy = p / W_, x0 = p % W_;
  const float* ib = in + (size_t)b * inStride;
  const float* w0r = w + (size_t)c0 * (2 * C_) * 9;
  const float* w1r = w0r + (size_t)(2 * C_) * 9;
  float a0 = 0.f, a1 = 0.f;
  int ci0 = half * C_;
#pragma unroll 2
  for (int ci = ci0; ci < ci0 + C_; ++ci) {
    const float* ip = ib + ci * N_;
    const float* wp0 = w0r + ci * 9;
    const float* wp1 = w1r + ci * 9;
#pragma unroll
    for (int ky = 0; ky < 3; ++ky) {
      int iyy = yy + ky - 1;
      if ((unsigned)iyy >= (unsigned)H_) continue;
      const float* rp = ip + iyy * W_;
      float vm = rp[x0];
      float vL = (x0 > 0)      ? rp[x0 - 1] : 0.f;
      float vR = (x0 + 1 < W_) ? rp[x0 + 1] : 0.f;
      a0 += vL * wp0[ky*3] + vm * wp0[ky*3+1] + vR * wp0[ky*3+2];
      a1 += vL * wp1[ky*3] + vm * wp1[ky*3+1] + vR * wp1[ky*3+2];
    }
  }
  float* ob = (half ? outB + (size_t)b * outStrideB
                    : outA + (size_t)b * outStrideA);
  size_t o = (size_t)c0 * N_ + p;
  ob[o]      = a0;
  ob[o + N_] = a1;
}

// ------ combine halves + bn + relu, float4 (in-place into A ok) -----------
// grid 576, block 256. half0 at pA + b*strideA, half1 at pB + b*strideB.
__global__ void k_comb(const float* __restrict__ pA, size_t strideA,
                       const float* __restrict__ pB, size_t strideB,
                       const float* __restrict__ g, const float* __restrict__ b2,
                       const float* __restrict__ m, const float* __restrict__ v,
                       float* __restrict__ out, size_t outStride) {
  int t = blockIdx.x * 256 + threadIdx.x;
  int p4 = t * 4;
  int n = p4 % N_;
  int c = (p4 / N_) % (2 * C_);
  int b = p4 / (2 * C_ * N_);
  size_t off = (size_t)c * N_ + n;
  float4 a = *(const float4*)(pA + (size_t)b * strideA + off);
  float4 d = *(const float4*)(pB + (size_t)b * strideB + off);
  float s  = g[c] * rsqrtf(v[c] + EPS_);
  float sh = b2[c] - m[c] * s;
  float4 r;
  r.x = fmaxf((a.x + d.x) * s + sh, 0.f);
  r.y = fmaxf((a.y + d.y) * s + sh, 0.f);
  r.z = fmaxf((a.z + d.z) * s + sh, 0.f);
  r.w = fmaxf((a.w + d.w) * s + sh, 0.f);
  *(float4*)(out + (size_t)b * outStride + off) = r;
}

// -------- final 1x1 conv over fused comb(pA,pB)+bn+relu, + cat add --------
// grid (18, 2C, B), block 64. bn scale/shift precomputed into LDS.
__global__ __launch_bounds__(64) void k_final3(
    const float* __restrict__ pA, size_t strideA,
    const float* __restrict__ pB, size_t strideB,
    const float* __restrict__ g2, const float* __restrict__ b2,
    const float* __restrict__ m2, const float* __restrict__ v2,
    const float* __restrict__ cat,
    const float* __restrict__ w, const float* __restrict__ fb,
    float* __restrict__ out) {
  __shared__ float fsc[2 * C_], fsh[2 * C_];
  for (int j = threadIdx.x; j < 2 * C_; j += 64) {
    float s = g2[j] * rsqrtf(v2[j] + EPS_);
    fsc[j] = s;
    fsh[j] = b2[j] - m2[j] * s;
  }
  __syncthreads();
  int p = blockIdx.x * 128 + threadIdx.x * 2;
  int c = blockIdx.y, b = blockIdx.z;
  const float* frA = pA + (size_t)b * strideA;
  const float* frB = pB + (size_t)b * strideB;
  const float* wr = w + (size_t)c * 2 * C_;
  float a0 = fb[c], a1 = a0;
  for (int j = 0; j < 2 * C_; ++j) {
    float2 fa = *(const float2*)(frA + (size_t)j * N_ + p);
    float2 fd = *(const float2*)(frB + (size_t)j * N_ + p);
    float s = fsc[j], sh = fsh[j];
    float f0 = fmaxf((fa.x + fd.x) * s + sh, 0.f);
    float f1 = fmaxf((fa.y + fd.y) * s + sh, 0.f);
    float wv = wr[j];
    a0 += wv * f0; a1 += wv * f1;
  }
  size_t o = ((size_t)b * 2 * C_ + c) * N_ + p;
  float2 cv = *(const float2*)(cat + o);
  *(float2*)(out + o) = make_float2(a0 + cv.x, a1 + cv.y);
}

extern "C" void kernel_launch(void* const* d_in, const int* in_sizes, int n_in,
                              void* d_out, int out_size, void* d_ws, size_t ws_size,
                              hipStream_t stream) {
  const float* x       = (const float*)d_in[0];
  const float* y       = (const float*)d_in[1];
  const float* pconv_w = (const float*)d_in[2];
  const float* pconv_b = (const float*)d_in[3];
  const float* bnd_g = (const float*)d_in[4];
  const float* bnd_b = (const float*)d_in[5];
  const float* bnd_m = (const float*)d_in[6];
  const float* bnd_v = (const float*)d_in[7];
  const float* lnx_g = (const float*)d_in[8];
  const float* lnx_b = (const float*)d_in[9];
  const float* lny_g = (const float*)d_in[10];
  const float* lny_b = (const float*)d_in[11];
  const float* lnz_g = (const float*)d_in[12];
  const float* lnz_b = (const float*)d_in[13];
  const float* k_w   = (const float*)d_in[14];
  const float* k_b   = (const float*)d_in[15];
  const float* qv_w  = (const float*)d_in[16];
  const float* qv_b  = (const float*)d_in[17];
  const float* proj_w = (const float*)d_in[18];
  const float* proj_b = (const float*)d_in[19];
  const float* c2w1  = (const float*)d_in[20];
  const float* c2b1  = (const float*)d_in[21];
  const float* c2bn1_g = (const float*)d_in[22];
  const float* c2bn1_b = (const float*)d_in[23];
  const float* c2bn1_m = (const float*)d_in[24];
  const float* c2bn1_v = (const float*)d_in[25];
  const float* c2w2  = (const float*)d_in[26];
  const float* c2b2  = (const float*)d_in[27];
  const float* c2bn2_g = (const float*)d_in[28];
  const float* c2bn2_b = (const float*)d_in[29];
  const float* c2bn2_m = (const float*)d_in[30];
  const float* c2bn2_v = (const float*)d_in[31];
  const float* bn2_g = (const float*)d_in[32];
  const float* bn2_b = (const float*)d_in[33];
  const float* bn2_m = (const float*)d_in[34];
  const float* bn2_v = (const float*)d_in[35];
  const float* f1w   = (const float*)d_in[36];
  const float* fbn1_g = (const float*)d_in[37];
  const float* fbn1_b = (const float*)d_in[38];
  const float* fbn1_m = (const float*)d_in[39];
  const float* fbn1_v = (const float*)d_in[40];
  const float* f2w   = (const float*)d_in[41];
  const float* fbn2_g = (const float*)d_in[42];
  const float* fbn2_b = (const float*)d_in[43];
  const float* fbn2_m = (const float*)d_in[44];
  const float* fbn2_v = (const float*)d_in[45];
  const float* f3w   = (const float*)d_in[46];
  const float* f3b   = (const float*)d_in[47];

  // 8-slot workspace plan (same as R12):
  //   A: k_pre -> xl(1) yl(2) zl(3)
  //   B: qvk -> xq(4) xv(5) yq(6) yv(7); kk(0)
  //   C: attn7 -> att_xo(1) att_yo(2)
  //   D: proj -> xo4(3,4) [z*CN]
  //   E: convp -> tmp(5,6) [z*CN]
  //   F: conv2b -> o2(1,2) [z*CN]; reads tmp(5,6), resid(3,4)
  //   G: catbn -> cat(3,4), fin b0->sl0, b1->sl7 (finStride 7S)
  //   H1: fconvs f1: fin(0/7) -> half0 (1,2 stride S), half1 (5,6 stride S)
  //   H2: comb -> (1,2) in-place
  //   H3: fconvs f2: (1,2) -> half0 (5,6), half1 (0/7)
  //   I: final3 reads partials (5,6)+(0/7), cat(3,4) -> out
  float* ws = (float*)d_ws;
  float* sl0 = ws + 0 * S_;
  float* sl1 = ws + 1 * S_;
  float* sl2 = ws + 2 * S_;
  float* sl3 = ws + 3 * S_;
  float* sl4 = ws + 4 * S_;
  float* sl5 = ws + 5 * S_;

  // A. fused pconv + bn + ln
  k_pre<<<B_ * N_, 64, 0, stream>>>(x, y, pconv_w, pconv_b,
                                    bnd_g, bnd_b, bnd_m, bnd_v,
                                    lnx_g, lnx_b, lny_g, lny_b, lnz_g, lnz_b,
                                    sl1, sl2, sl3);
  // B. fused qv + kproj
  {
    dim3 g(2304, 1, 3);
    k_qvk<<<g, 256, 0, stream>>>(sl1, sl3, qv_w, qv_b, k_w, k_b, sl4, sl5, sl0);
  }
  // C. attention v7 -> att_xo(1), att_yo(2)
  {
    dim3 g(N_ / 64, B_ * NH_);
    k_attn7<<<g, 1024, 0, stream>>>(sl4, sl5, ws + 6 * S_, ws + 7 * S_, sl0,
                                    sl1, sl2);
  }
  // D. proj batched -> xo4(3,4)
  {
    dim3 g(18, C_, 2 * B_);
    k_proj2<<<g, 64, 0, stream>>>(sl1, x, y, bnd_g, bnd_b, bnd_m, bnd_v,
                                  proj_w, proj_b, sl3);
  }
  // E. conv1, per-image, 1 px/thread -> tmp(5,6)
  {
    dim3 g(36, C_ / 2, 2 * B_);
    k_convp<<<g, 64, 0, stream>>>(sl3, c2w1, c2b1,
        c2bn1_g, c2bn1_b, c2bn1_m, c2bn1_v, sl5);
  }
  // F. conv2 + bn + relu + resid, per-image, 1 px/thread -> o2(1,2)
  {
    dim3 g(36, C_ / 2, 2 * B_);
    k_conv2b<<<g, 64, 0, stream>>>(sl5, c2w2, c2b2,
        c2bn2_g, c2bn2_b, c2bn2_m, c2bn2_v, sl3, sl1);
  }
  // G. cat + bn2 -> cat(3,4), fin(0 / 7)
  k_catbn<<<576, 256, 0, stream>>>(sl1, bn2_g, bn2_b, bn2_m, bn2_v,
                                   sl3, sl0, 7 * S_);
  // H. f-branch convs, ci-split, 1 px/thread
  {
    dim3 g(36, C_, 2 * B_);
    k_fconvs<<<g, 64, 0, stream>>>(sl0, 7 * S_, f1w, sl1, S_, sl5, S_);
    k_comb<<<576, 256, 0, stream>>>(sl1, S_, sl5, S_,
                                    fbn1_g, fbn1_b, fbn1_m, fbn1_v, sl1, S_);
    k_fconvs<<<g, 64, 0, stream>>>(sl1, S_, f2w, sl5, S_, sl0, 7 * S_);
  }
  // I. final 1x1 fused with comb(fbn2) + cat add -> fp32 out
  {
    dim3 g(18, 2 * C_, B_);
    k_final3<<<g, 64, 0, stream>>>(sl5, S_, sl0, 7 * S_,
                                   fbn2_g, fbn2_b, fbn2_m, fbn2_v,
                                   sl3, f3w, f3b, (float*)d_out);
  }
}

// Round 14
// 698.679 us; speedup vs baseline: 1.0544x; 1.0544x over previous
//
#include <hip/hip_runtime.h>
#include <hip/hip_bf16.h>

#define B_   2
#define C_   64
#define H_   48
#define W_   48
#define N_   (H_*W_)     // 2304
#define NH_  8
#define HD_  8
#define EPS_ 1e-5f
#define S2_  0.125f      // scale^2 = 1/hd
#define LOG2E_ 1.44269504f
#define S_   ((size_t)B_ * C_ * N_)   // 294912 floats per workspace slot
#define CN_  ((size_t)C_ * N_)        // 147456 floats per image

__device__ __forceinline__ float wsum64(float v) {
#pragma unroll
  for (int o = 32; o > 0; o >>= 1) v += __shfl_xor(v, o, 64);
  return v;
}

__device__ __forceinline__ float ln_val(float t, float g, float b) {
  float mu  = wsum64(t) * (1.0f / 64.0f);
  float d   = t - mu;
  float var = wsum64(d * d) * (1.0f / 64.0f);
  return d * rsqrtf(var + EPS_) * g + b;
}

// ---- fused 1x1 pconv + BN + 3x LayerNorm; block = one (b,n) row ----------
__global__ __launch_bounds__(64) void k_pre(
    const float* __restrict__ x, const float* __restrict__ y,
    const float* __restrict__ pw, const float* __restrict__ pb,
    const float* g, const float* bb, const float* m, const float* v,
    const float* lnxg, const float* lnxb,
    const float* lnyg, const float* lnyb,
    const float* lnzg, const float* lnzb,
    float* __restrict__ xl, float* __restrict__ yl, float* __restrict__ zl) {
  __shared__ float xs[64], ys[64];
  int row = blockIdx.x;            // b*N + n
  int c = threadIdx.x;
  int b = row / N_, n = row % N_;
  float xv = x[(size_t)(b * C_ + c) * N_ + n];
  float yv = y[(size_t)(b * C_ + c) * N_ + n];
  xs[c] = xv; ys[c] = yv;
  __syncthreads();
  const float4* wr  = (const float4*)(pw + (size_t)c * 2 * C_);
  const float4* xs4 = (const float4*)xs;
  const float4* ys4 = (const float4*)ys;
  float acc = pb[c];
#pragma unroll
  for (int t = 0; t < 16; ++t) {
    float4 a = xs4[t], wv = wr[t];
    acc += a.x * wv.x + a.y * wv.y + a.z * wv.z + a.w * wv.w;
  }
#pragma unroll
  for (int t = 0; t < 16; ++t) {
    float4 a = ys4[t], wv = wr[16 + t];
    acc += a.x * wv.x + a.y * wv.y + a.z * wv.z + a.w * wv.w;
  }
  float s  = g[c] * rsqrtf(v[c] + EPS_);
  float sh = bb[c] - m[c] * s;
  float tx = xv * s + sh;
  xl[(size_t)row * C_ + c] = ln_val(tx, lnxg[c], lnxb[c]);
  float ty = yv * s + sh;
  yl[(size_t)row * C_ + c] = ln_val(ty, lnyg[c], lnyb[c]);
  float tz = acc * s + sh;
  zl[(size_t)row * C_ + c] = ln_val(tz, lnzg[c], lnzb[c]);
}

// ------------- fused qv (both branches) + k projection --------------------
__global__ void k_qvk(const float* __restrict__ lnb, const float* __restrict__ zl,
                      const float* __restrict__ qvw, const float* __restrict__ qvb,
                      const float* __restrict__ kw, const float* __restrict__ kb,
                      float* __restrict__ qb, float* __restrict__ vb,
                      float* __restrict__ kk) {
  int z = blockIdx.z;
  if (z < 2) {
    int idx = blockIdx.x * 256 + threadIdx.x;   // B*N*128
    int j = idx & 127;
    int row = idx >> 7;
    int b = row / N_, n = row % N_;
    const float4* ir = (const float4*)(lnb + z * S_ + (size_t)row * C_);
    const float4* wr = (const float4*)(qvw + (size_t)j * C_);
    float acc = qvb[j];
#pragma unroll
    for (int t = 0; t < 16; ++t) {
      float4 a = ir[t], wv = wr[t];
      acc += a.x * wv.x + a.y * wv.y + a.z * wv.z + a.w * wv.w;
    }
    int jj = j & 63;
    int h = jj >> 3, d = jj & 7;
    float* dst = ((j < C_) ? qb : vb) + z * 2 * S_;
    dst[((size_t)(b * NH_ + h) * N_ + n) * HD_ + d] = acc;
  } else {
    if (blockIdx.x >= 1152) return;
    int idx = blockIdx.x * 256 + threadIdx.x;   // B*N*64
    int j = idx & 63;
    int row = idx >> 6;
    int b = row / N_, n = row % N_;
    const float4* ir = (const float4*)(zl + (size_t)row * C_);
    const float4* wr = (const float4*)(kw + (size_t)j * C_);
    float acc = kb[j];
#pragma unroll
    for (int t = 0; t < 16; ++t) {
      float4 a = ir[t], wv = wr[t];
      acc += a.x * wv.x + a.y * wv.y + a.z * wv.z + a.w * wv.w;
    }
    int h = j >> 3, d = j & 7;
    kk[((size_t)(b * NH_ + h) * N_ + n) * HD_ + d] = acc;
  }
}

// ---------------- attention v7: 16 waves, no-max, 2-key ILP ---------------
#define AW 16
__global__ __launch_bounds__(1024, 8) void k_attn7(
    const float* __restrict__ xq, const float* __restrict__ xv,
    const float* __restrict__ yq, const float* __restrict__ yv,
    const float* __restrict__ kk,
    float* __restrict__ outx, float* __restrict__ outy) {
  __shared__ float pl[AW][64];
  __shared__ float pbuf[AW][8][64];
  int bh  = blockIdx.y;
  int qt  = blockIdx.x;
  int tid = threadIdx.x;
  int lane = tid & 63;
  int wave = __builtin_amdgcn_readfirstlane(tid >> 6);
  int q = qt * 64 + lane;
  size_t base = (size_t)bh * N_ * HD_;

  float4 qx0 = ((const float4*)(xq + base + (size_t)q * HD_))[0];
  float4 qx1 = ((const float4*)(xq + base + (size_t)q * HD_))[1];
  float4 qy0 = ((const float4*)(yq + base + (size_t)q * HD_))[0];
  float4 qy1 = ((const float4*)(yq + base + (size_t)q * HD_))[1];
  const float fs = S2_ * LOG2E_;
  qx0.x *= fs; qx0.y *= fs; qx0.z *= fs; qx0.w *= fs;
  qx1.x *= fs; qx1.y *= fs; qx1.z *= fs; qx1.w *= fs;

  float l = 0.f;
  float ax[8] = {0,0,0,0,0,0,0,0};
  float ay[8] = {0,0,0,0,0,0,0,0};

  const float4* kp = (const float4*)(kk + base);
  const float4* xp = (const float4*)(xv + base);
  const float4* yp = (const float4*)(yv + base);
  int k0 = wave * (N_ / AW);
  for (int mi = k0; mi < k0 + N_ / AW; mi += 2) {
    float4 kaA  = kp[2 * mi],     kbA = kp[2 * mi + 1];
    float4 kaB  = kp[2 * mi + 2], kbB = kp[2 * mi + 3];
    float4 xaA = xp[2 * mi],     xbA = xp[2 * mi + 1];
    float4 xaB = xp[2 * mi + 2], xbB = xp[2 * mi + 3];
    float4 yaA = yp[2 * mi],     ybA = yp[2 * mi + 1];
    float4 yaB = yp[2 * mi + 2], ybB = yp[2 * mi + 3];
    float s1A = qx0.x*kaA.x + qx0.y*kaA.y + qx0.z*kaA.z + qx0.w*kaA.w
              + qx1.x*kbA.x + qx1.y*kbA.y + qx1.z*kbA.z + qx1.w*kbA.w;
    float s2A = qy0.x*kaA.x + qy0.y*kaA.y + qy0.z*kaA.z + qy0.w*kaA.w
              + qy1.x*kbA.x + qy1.y*kbA.y + qy1.z*kbA.z + qy1.w*kbA.w;
    float s1B = qx0.x*kaB.x + qx0.y*kaB.y + qx0.z*kaB.z + qx0.w*kaB.w
              + qx1.x*kbB.x + qx1.y*kbB.y + qx1.z*kbB.z + qx1.w*kbB.w;
    float s2B = qy0.x*kaB.x + qy0.y*kaB.y + qy0.z*kaB.z + qy0.w*kaB.w
              + qy1.x*kbB.x + qy1.y*kbB.y + qy1.z*kbB.z + qy1.w*kbB.w;
    float pA = exp2f(s1A * s2A);
    float pB = exp2f(s1B * s2B);
    l += pA + pB;
    ax[0] += pA*xaA.x + pB*xaB.x;  ax[1] += pA*xaA.y + pB*xaB.y;
    ax[2] += pA*xaA.z + pB*xaB.z;  ax[3] += pA*xaA.w + pB*xaB.w;
    ax[4] += pA*xbA.x + pB*xbB.x;  ax[5] += pA*xbA.y + pB*xbB.y;
    ax[6] += pA*xbA.z + pB*xbB.z;  ax[7] += pA*xbA.w + pB*xbB.w;
    ay[0] += pA*yaA.x + pB*yaB.x;  ay[1] += pA*yaA.y + pB*yaB.y;
    ay[2] += pA*yaA.z + pB*yaB.z;  ay[3] += pA*yaA.w + pB*yaB.w;
    ay[4] += pA*ybA.x + pB*ybB.x;  ay[5] += pA*ybA.y + pB*ybB.y;
    ay[6] += pA*ybA.z + pB*ybB.z;  ay[7] += pA*ybA.w + pB*ybB.w;
  }
  pl[wave][lane] = l;
#pragma unroll
  for (int d = 0; d < 8; ++d) pbuf[wave][d][lane] = ax[d];
  __syncthreads();
  float Linv = 0.f;
  int b = bh / NH_, h = bh % NH_;
  if (tid < 64) {
    float L = 0.f;
#pragma unroll
    for (int w = 0; w < AW; ++w) L += pl[w][lane];
    Linv = 1.f / L;
    float A[8] = {0,0,0,0,0,0,0,0};
#pragma unroll
    for (int w = 0; w < AW; ++w)
#pragma unroll
      for (int d = 0; d < 8; ++d) A[d] += pbuf[w][d][lane];
    float* o = outx + ((size_t)(b * N_ + q)) * C_ + h * HD_;
#pragma unroll
    for (int d = 0; d < 8; ++d) o[d] = A[d] * Linv;
  }
  __syncthreads();
#pragma unroll
  for (int d = 0; d < 8; ++d) pbuf[wave][d][lane] = ay[d];
  __syncthreads();
  if (tid < 64) {
    float A[8] = {0,0,0,0,0,0,0,0};
#pragma unroll
    for (int w = 0; w < AW; ++w)
#pragma unroll
      for (int d = 0; d < 8; ++d) A[d] += pbuf[w][d][lane];
    float* o = outy + ((size_t)(b * N_ + q)) * C_ + h * HD_;
#pragma unroll
    for (int d = 0; d < 8; ++d) o[d] = A[d] * Linv;
  }
}

// -------- proj + recomputed-BN residual, 2 px/thread ----------------------
// grid (18, C_, 2*B_), block 64. out layout z*CN, z = branch*B_ + b.
__global__ __launch_bounds__(64) void k_proj2(
    const float* __restrict__ attbase,
    const float* __restrict__ x, const float* __restrict__ y,
    const float* bg, const float* bb2, const float* bm, const float* bv,
    const float* __restrict__ pw, const float* __restrict__ pbias,
    float* __restrict__ outbase) {
  int p = blockIdx.x * 128 + threadIdx.x * 2;
  int c = blockIdx.y;
  int z = blockIdx.z;
  int branch = z >> 1, b = z & 1;
  const float* att = attbase + branch * S_ + (size_t)b * N_ * C_;
  const float4* wr = (const float4*)(pw + (size_t)c * C_);
  float bias = pbias[c];
  float acc[2];
#pragma unroll
  for (int i = 0; i < 2; ++i) {
    const float4* ar = (const float4*)(att + (size_t)(p + i) * C_);
    float a = bias;
#pragma unroll
    for (int t = 0; t < 16; ++t) {
      float4 av = ar[t], wv = wr[t];
      a += av.x * wv.x + av.y * wv.y + av.z * wv.z + av.w * wv.w;
    }
    acc[i] = a;
  }
  float s  = bg[c] * rsqrtf(bv[c] + EPS_);
  float sh = bb2[c] - bm[c] * s;
  const float* xin = branch ? y : x;
  float2 r = *(const float2*)(xin + ((size_t)b * C_ + c) * N_ + p);
  size_t o = (size_t)z * CN_ + (size_t)c * N_ + p;
  *(float2*)(outbase + o) = make_float2(acc[0] + r.x * s + sh,
                                        acc[1] + r.y * s + sh);
}

// ------ conv1: one image per z, 2 couts + 2 px per thread -----------------
// grid (18, C_/2, 2*B_), block 64. z = branch*B_ + b (layout z*CN).
__global__ __launch_bounds__(64) void k_convp(
    const float* __restrict__ in, const float* __restrict__ w,
    const float* __restrict__ cb,
    const float* __restrict__ bg, const float* __restrict__ bbeta,
    const float* __restrict__ bm, const float* __restrict__ bv,
    float* __restrict__ out) {
  int p = blockIdx.x * 128 + threadIdx.x * 2;
  int c0 = blockIdx.y * 2;
  int z = blockIdx.z;
  int yy = p / W_, x0 = p % W_;
  const float* ib = in + (size_t)z * CN_;
  const float* w0r = w + (size_t)c0 * C_ * 9;
  const float* w1r = w0r + (size_t)C_ * 9;
  float bias0 = cb[c0], bias1 = cb[c0 + 1];
  float a00 = bias0, a01 = bias0, a10 = bias1, a11 = bias1;
#pragma unroll 2
  for (int ci = 0; ci < C_; ++ci) {
    const float* ip = ib + ci * N_;
    const float* wp0 = w0r + ci * 9;
    const float* wp1 = w1r + ci * 9;
#pragma unroll
    for (int ky = 0; ky < 3; ++ky) {
      int iyy = yy + ky - 1;
      if ((unsigned)iyy >= (unsigned)H_) continue;
      const float* rp = ip + iyy * W_;
      float2 mid = *(const float2*)(rp + x0);
      float vL = (x0 > 0) ? rp[x0 - 1] : 0.f;
      float vR = (x0 + 2 < W_) ? rp[x0 + 2] : 0.f;
      float u0 = wp0[ky*3], u1 = wp0[ky*3+1], u2 = wp0[ky*3+2];
      float t0 = wp1[ky*3], t1 = wp1[ky*3+1], t2 = wp1[ky*3+2];
      a00 += vL*u0 + mid.x*u1 + mid.y*u2;
      a01 += mid.x*u0 + mid.y*u1 + vR*u2;
      a10 += vL*t0 + mid.x*t1 + mid.y*t2;
      a11 += mid.x*t0 + mid.y*t1 + vR*t2;
    }
  }
  float s0 = bg[c0] * rsqrtf(bv[c0] + EPS_);
  float sh0 = bbeta[c0] - bm[c0] * s0;
  float s1 = bg[c0+1] * rsqrtf(bv[c0+1] + EPS_);
  float sh1 = bbeta[c0+1] - bm[c0+1] * s1;
  size_t o = (size_t)z * CN_ + (size_t)c0 * N_ + p;
  *(float2*)(out + o)      = make_float2(fmaxf(a00*s0+sh0,0.f), fmaxf(a01*s0+sh0,0.f));
  *(float2*)(out + o + N_) = make_float2(fmaxf(a10*s1+sh1,0.f), fmaxf(a11*s1+sh1,0.f));
}

// ------ conv2 + bn + relu + resid, one image per z, 2 couts + 2 px --------
// grid (18, C_/2, 2*B_), block 64. in/resid/out layout z*CN.
__global__ __launch_bounds__(64) void k_conv2b(
    const float* __restrict__ in, const float* __restrict__ w,
    const float* __restrict__ cb,
    const float* __restrict__ bg, const float* __restrict__ bbeta,
    const float* __restrict__ bm, const float* __restrict__ bv,
    const float* __restrict__ resid, float* __restrict__ out) {
  int p = blockIdx.x * 128 + threadIdx.x * 2;
  int c0 = blockIdx.y * 2;
  int z = blockIdx.z;
  int yy = p / W_, x0 = p % W_;
  const float* ib = in + (size_t)z * CN_;
  const float* w0r = w + (size_t)c0 * C_ * 9;
  const float* w1r = w0r + (size_t)C_ * 9;
  float bias0 = cb[c0], bias1 = cb[c0 + 1];
  float a00 = bias0, a01 = bias0, a10 = bias1, a11 = bias1;
#pragma unroll 2
  for (int ci = 0; ci < C_; ++ci) {
    const float* ip = ib + ci * N_;
    const float* wp0 = w0r + ci * 9;
    const float* wp1 = w1r + ci * 9;
#pragma unroll
    for (int ky = 0; ky < 3; ++ky) {
      int iyy = yy + ky - 1;
      if ((unsigned)iyy >= (unsigned)H_) continue;
      const float* rp = ip + iyy * W_;
      float2 mid = *(const float2*)(rp + x0);
      float vL = (x0 > 0) ? rp[x0 - 1] : 0.f;
      float vR = (x0 + 2 < W_) ? rp[x0 + 2] : 0.f;
      float u0 = wp0[ky*3], u1 = wp0[ky*3+1], u2 = wp0[ky*3+2];
      float t0 = wp1[ky*3], t1 = wp1[ky*3+1], t2 = wp1[ky*3+2];
      a00 += vL*u0 + mid.x*u1 + mid.y*u2;
      a01 += mid.x*u0 + mid.y*u1 + vR*u2;
      a10 += vL*t0 + mid.x*t1 + mid.y*t2;
      a11 += mid.x*t0 + mid.y*t1 + vR*t2;
    }
  }
  float s0 = bg[c0] * rsqrtf(bv[c0] + EPS_);
  float sh0 = bbeta[c0] - bm[c0] * s0;
  float s1 = bg[c0+1] * rsqrtf(bv[c0+1] + EPS_);
  float sh1 = bbeta[c0+1] - bm[c0+1] * s1;
  size_t o = (size_t)z * CN_ + (size_t)c0 * N_ + p;
  float2 r0 = *(const float2*)(resid + o);
  float2 r1 = *(const float2*)(resid + o + N_);
  *(float2*)(out + o)      = make_float2(fmaxf(a00*s0+sh0,0.f) + r0.x,
                                         fmaxf(a01*s0+sh0,0.f) + r0.y);
  *(float2*)(out + o + N_) = make_float2(fmaxf(a10*s1+sh1,0.f) + r1.x,
                                         fmaxf(a11*s1+sh1,0.f) + r1.y);
}

// ------ cat = [xo+yo ; xo*yo] + bn2 -> fin, float4 ------------------------
// grid 576, block 256. o2 layout z*CN (z=branch*B+b). fin b at fin+b*finStride.
__global__ void k_catbn(const float* __restrict__ o2,
                        const float* __restrict__ g, const float* __restrict__ b2,
                        const float* __restrict__ m, const float* __restrict__ v,
                        float* __restrict__ cat, float* __restrict__ fin,
                        size_t finStride) {
  int t = blockIdx.x * 256 + threadIdx.x;
  int p4 = t * 4;
  int n  = p4 % N_;
  int c2 = (p4 / N_) % (2 * C_);
  int b  = p4 / (2 * C_ * N_);
  int c  = c2 & 63;
  float4 X = *(const float4*)(o2 + (size_t)b * CN_ + (size_t)c * N_ + n);
  float4 Y = *(const float4*)(o2 + (size_t)(2 + b) * CN_ + (size_t)c * N_ + n);
  float4 val;
  if (c2 < C_) val = make_float4(X.x + Y.x, X.y + Y.y, X.z + Y.z, X.w + Y.w);
  else         val = make_float4(X.x * Y.x, X.y * Y.y, X.z * Y.z, X.w * Y.w);
  size_t co = ((size_t)b * 2 * C_ + c2) * N_ + n;
  *(float4*)(cat + co) = val;
  float s  = g[c2] * rsqrtf(v[c2] + EPS_);
  float sh = b2[c2] - m[c2] * s;
  *(float4*)(fin + (size_t)b * finStride + (size_t)c2 * N_ + n) =
      make_float4(val.x * s + sh, val.y * s + sh, val.z * s + sh, val.w * s + sh);
}

// ------ f-branch 3x3 conv partial (64-cin half), 2 couts + 2 px -----------
// grid (18, C_, 2*B_), block 64. z: b = z&1, half = z>>1.
__global__ __launch_bounds__(64) void k_fconvs(
    const float* __restrict__ in, size_t inStride,
    const float* __restrict__ w,
    float* __restrict__ outA, size_t outStrideA,
    float* __restrict__ outB, size_t outStrideB) {
  int p = blockIdx.x * 128 + threadIdx.x * 2;
  int c0 = blockIdx.y * 2;
  int z = blockIdx.z;
  int b = z & 1, half = z >> 1;
  int yy = p / W_, x0 = p % W_;
  const float* ib = in + (size_t)b * inStride;
  const float* w0r = w + (size_t)c0 * (2 * C_) * 9;
  const float* w1r = w0r + (size_t)(2 * C_) * 9;
  float a00 = 0.f, a01 = 0.f, a10 = 0.f, a11 = 0.f;
  int ci0 = half * C_;
#pragma unroll 2
  for (int ci = ci0; ci < ci0 + C_; ++ci) {
    const float* ip = ib + ci * N_;
    const float* wp0 = w0r + ci * 9;
    const float* wp1 = w1r + ci * 9;
#pragma unroll
    for (int ky = 0; ky < 3; ++ky) {
      int iyy = yy + ky - 1;
      if ((unsigned)iyy >= (unsigned)H_) continue;
      const float* rp = ip + iyy * W_;
      float2 mid = *(const float2*)(rp + x0);
      float vL = (x0 > 0) ? rp[x0 - 1] : 0.f;
      float vR = (x0 + 2 < W_) ? rp[x0 + 2] : 0.f;
      float u0 = wp0[ky*3], u1 = wp0[ky*3+1], u2 = wp0[ky*3+2];
      float t0 = wp1[ky*3], t1 = wp1[ky*3+1], t2 = wp1[ky*3+2];
      a00 += vL*u0 + mid.x*u1 + mid.y*u2;
      a01 += mid.x*u0 + mid.y*u1 + vR*u2;
      a10 += vL*t0 + mid.x*t1 + mid.y*t2;
      a11 += mid.x*t0 + mid.y*t1 + vR*t2;
    }
  }
  float* ob = (half ? outB + (size_t)b * outStrideB
                    : outA + (size_t)b * outStrideA);
  size_t o = (size_t)c0 * N_ + p;
  *(float2*)(ob + o)      = make_float2(a00, a01);
  *(float2*)(ob + o + N_) = make_float2(a10, a11);
}

// ------ combine halves + bn + relu, float4 (in-place into A ok) -----------
// grid 576, block 256. half0 at pA + b*strideA, half1 at pB + b*strideB.
__global__ void k_comb(const float* __restrict__ pA, size_t strideA,
                       const float* __restrict__ pB, size_t strideB,
                       const float* __restrict__ g, const float* __restrict__ b2,
                       const float* __restrict__ m, const float* __restrict__ v,
                       float* __restrict__ out, size_t outStride) {
  int t = blockIdx.x * 256 + threadIdx.x;
  int p4 = t * 4;
  int n = p4 % N_;
  int c = (p4 / N_) % (2 * C_);
  int b = p4 / (2 * C_ * N_);
  size_t off = (size_t)c * N_ + n;
  float4 a = *(const float4*)(pA + (size_t)b * strideA + off);
  float4 d = *(const float4*)(pB + (size_t)b * strideB + off);
  float s  = g[c] * rsqrtf(v[c] + EPS_);
  float sh = b2[c] - m[c] * s;
  float4 r;
  r.x = fmaxf((a.x + d.x) * s + sh, 0.f);
  r.y = fmaxf((a.y + d.y) * s + sh, 0.f);
  r.z = fmaxf((a.z + d.z) * s + sh, 0.f);
  r.w = fmaxf((a.w + d.w) * s + sh, 0.f);
  *(float4*)(out + (size_t)b * outStride + off) = r;
}

// -------- final 1x1 conv over fused comb(pA,pB)+bn+relu, + cat add --------
// grid (18, 2C, B), block 64. bn scale/shift precomputed into LDS.
__global__ __launch_bounds__(64) void k_final3(
    const float* __restrict__ pA, size_t strideA,
    const float* __restrict__ pB, size_t strideB,
    const float* __restrict__ g2, const float* __restrict__ b2,
    const float* __restrict__ m2, const float* __restrict__ v2,
    const float* __restrict__ cat,
    const float* __restrict__ w, const float* __restrict__ fb,
    float* __restrict__ out) {
  __shared__ float fsc[2 * C_], fsh[2 * C_];
  for (int j = threadIdx.x; j < 2 * C_; j += 64) {
    float s = g2[j] * rsqrtf(v2[j] + EPS_);
    fsc[j] = s;
    fsh[j] = b2[j] - m2[j] * s;
  }
  __syncthreads();
  int p = blockIdx.x * 128 + threadIdx.x * 2;
  int c = blockIdx.y, b = blockIdx.z;
  const float* frA = pA + (size_t)b * strideA;
  const float* frB = pB + (size_t)b * strideB;
  const float* wr = w + (size_t)c * 2 * C_;
  float a0 = fb[c], a1 = a0;
  for (int j = 0; j < 2 * C_; ++j) {
    float2 fa = *(const float2*)(frA + (size_t)j * N_ + p);
    float2 fd = *(const float2*)(frB + (size_t)j * N_ + p);
    float s = fsc[j], sh = fsh[j];
    float f0 = fmaxf((fa.x + fd.x) * s + sh, 0.f);
    float f1 = fmaxf((fa.y + fd.y) * s + sh, 0.f);
    float wv = wr[j];
    a0 += wv * f0; a1 += wv * f1;
  }
  size_t o = ((size_t)b * 2 * C_ + c) * N_ + p;
  float2 cv = *(const float2*)(cat + o);
  *(float2*)(out + o) = make_float2(a0 + cv.x, a1 + cv.y);
}

extern "C" void kernel_launch(void* const* d_in, const int* in_sizes, int n_in,
                              void* d_out, int out_size, void* d_ws, size_t ws_size,
                              hipStream_t stream) {
  const float* x       = (const float*)d_in[0];
  const float* y       = (const float*)d_in[1];
  const float* pconv_w = (const float*)d_in[2];
  const float* pconv_b = (const float*)d_in[3];
  const float* bnd_g = (const float*)d_in[4];
  const float* bnd_b = (const float*)d_in[5];
  const float* bnd_m = (const float*)d_in[6];
  const float* bnd_v = (const float*)d_in[7];
  const float* lnx_g = (const float*)d_in[8];
  const float* lnx_b = (const float*)d_in[9];
  const float* lny_g = (const float*)d_in[10];
  const float* lny_b = (const float*)d_in[11];
  const float* lnz_g = (const float*)d_in[12];
  const float* lnz_b = (const float*)d_in[13];
  const float* k_w   = (const float*)d_in[14];
  const float* k_b   = (const float*)d_in[15];
  const float* qv_w  = (const float*)d_in[16];
  const float* qv_b  = (const float*)d_in[17];
  const float* proj_w = (const float*)d_in[18];
  const float* proj_b = (const float*)d_in[19];
  const float* c2w1  = (const float*)d_in[20];
  const float* c2b1  = (const float*)d_in[21];
  const float* c2bn1_g = (const float*)d_in[22];
  const float* c2bn1_b = (const float*)d_in[23];
  const float* c2bn1_m = (const float*)d_in[24];
  const float* c2bn1_v = (const float*)d_in[25];
  const float* c2w2  = (const float*)d_in[26];
  const float* c2b2  = (const float*)d_in[27];
  const float* c2bn2_g = (const float*)d_in[28];
  const float* c2bn2_b = (const float*)d_in[29];
  const float* c2bn2_m = (const float*)d_in[30];
  const float* c2bn2_v = (const float*)d_in[31];
  const float* bn2_g = (const float*)d_in[32];
  const float* bn2_b = (const float*)d_in[33];
  const float* bn2_m = (const float*)d_in[34];
  const float* bn2_v = (const float*)d_in[35];
  const float* f1w   = (const float*)d_in[36];
  const float* fbn1_g = (const float*)d_in[37];
  const float* fbn1_b = (const float*)d_in[38];
  const float* fbn1_m = (const float*)d_in[39];
  const float* fbn1_v = (const float*)d_in[40];
  const float* f2w   = (const float*)d_in[41];
  const float* fbn2_g = (const float*)d_in[42];
  const float* fbn2_b = (const float*)d_in[43];
  const float* fbn2_m = (const float*)d_in[44];
  const float* fbn2_v = (const float*)d_in[45];
  const float* f3w   = (const float*)d_in[46];
  const float* f3b   = (const float*)d_in[47];

  // 8-slot workspace plan (same as R12):
  //   A: k_pre -> xl(1) yl(2) zl(3)
  //   B: qvk -> xq(4) xv(5) yq(6) yv(7); kk(0)
  //   C: attn7 -> att_xo(1) att_yo(2)
  //   D: proj -> xo4(3,4) [z*CN]
  //   E: convp -> tmp(5,6) [z*CN]
  //   F: conv2b -> o2(1,2) [z*CN]; reads tmp(5,6), resid(3,4)
  //   G: catbn -> cat(3,4), fin b0->sl0, b1->sl7 (finStride 7S)
  //   H1: fconvs f1: fin(0/7) -> half0 (1,2 stride S), half1 (5,6 stride S)
  //   H2: comb -> (1,2) in-place
  //   H3: fconvs f2: (1,2) -> half0 (5,6), half1 (0/7)
  //   I: final3 reads partials (5,6)+(0/7), cat(3,4) -> out
  float* ws = (float*)d_ws;
  float* sl0 = ws + 0 * S_;
  float* sl1 = ws + 1 * S_;
  float* sl2 = ws + 2 * S_;
  float* sl3 = ws + 3 * S_;
  float* sl4 = ws + 4 * S_;
  float* sl5 = ws + 5 * S_;

  // A. fused pconv + bn + ln
  k_pre<<<B_ * N_, 64, 0, stream>>>(x, y, pconv_w, pconv_b,
                                    bnd_g, bnd_b, bnd_m, bnd_v,
                                    lnx_g, lnx_b, lny_g, lny_b, lnz_g, lnz_b,
                                    sl1, sl2, sl3);
  // B. fused qv + kproj
  {
    dim3 g(2304, 1, 3);
    k_qvk<<<g, 256, 0, stream>>>(sl1, sl3, qv_w, qv_b, k_w, k_b, sl4, sl5, sl0);
  }
  // C. attention v7 -> att_xo(1), att_yo(2)
  {
    dim3 g(N_ / 64, B_ * NH_);
    k_attn7<<<g, 1024, 0, stream>>>(sl4, sl5, ws + 6 * S_, ws + 7 * S_, sl0,
                                    sl1, sl2);
  }
  // D. proj batched -> xo4(3,4)
  {
    dim3 g(18, C_, 2 * B_);
    k_proj2<<<g, 64, 0, stream>>>(sl1, x, y, bnd_g, bnd_b, bnd_m, bnd_v,
                                  proj_w, proj_b, sl3);
  }
  // E. conv1, per-image, 2 px/thread -> tmp(5,6)
  {
    dim3 g(18, C_ / 2, 2 * B_);
    k_convp<<<g, 64, 0, stream>>>(sl3, c2w1, c2b1,
        c2bn1_g, c2bn1_b, c2bn1_m, c2bn1_v, sl5);
  }
  // F. conv2 + bn + relu + resid, per-image, 2 px/thread -> o2(1,2)
  {
    dim3 g(18, C_ / 2, 2 * B_);
    k_conv2b<<<g, 64, 0, stream>>>(sl5, c2w2, c2b2,
        c2bn2_g, c2bn2_b, c2bn2_m, c2bn2_v, sl3, sl1);
  }
  // G. cat + bn2 -> cat(3,4), fin(0 / 7)
  k_catbn<<<576, 256, 0, stream>>>(sl1, bn2_g, bn2_b, bn2_m, bn2_v,
                                   sl3, sl0, 7 * S_);
  // H. f-branch convs, ci-split, 2 px/thread
  {
    dim3 g(18, C_, 2 * B_);
    k_fconvs<<<g, 64, 0, stream>>>(sl0, 7 * S_, f1w, sl1, S_, sl5, S_);
    k_comb<<<576, 256, 0, stream>>>(sl1, S_, sl5, S_,
                                    fbn1_g, fbn1_b, fbn1_m, fbn1_v, sl1, S_);
    k_fconvs<<<g, 64, 0, stream>>>(sl1, S_, f2w, sl5, S_, sl0, 7 * S_);
  }
  // I. final 1x1 fused with comb(fbn2) + cat add -> fp32 out
  {
    dim3 g(18, 2 * C_, B_);
    k_final3<<<g, 64, 0, stream>>>(sl5, S_, sl0, 7 * S_,
                                   fbn2_g, fbn2_b, fbn2_m, fbn2_v,
                                   sl3, f3w, f3b, (float*)d_out);
  }
}

// Round 15
// 654.879 us; speedup vs baseline: 1.1250x; 1.0669x over previous
//
#include <hip/hip_runtime.h>
#include <hip/hip_bf16.h>

#define B_   2
#define C_   64
#define H_   48
#define W_   48
#define N_   (H_*W_)     // 2304
#define NH_  8
#define HD_  8
#define EPS_ 1e-5f
#define S2_  0.125f      // scale^2 = 1/hd
#define LOG2E_ 1.44269504f
#define S_   ((size_t)B_ * C_ * N_)   // 294912 floats per workspace slot
#define CN_  ((size_t)C_ * N_)        // 147456 floats per image

__device__ __forceinline__ float wsum64(float v) {
#pragma unroll
  for (int o = 32; o > 0; o >>= 1) v += __shfl_xor(v, o, 64);
  return v;
}

__device__ __forceinline__ float ln_val(float t, float g, float b) {
  float mu  = wsum64(t) * (1.0f / 64.0f);
  float d   = t - mu;
  float var = wsum64(d * d) * (1.0f / 64.0f);
  return d * rsqrtf(var + EPS_) * g + b;
}

// ---- fused 1x1 pconv + BN + 3x LayerNorm; block = one (b,n) row ----------
__global__ __launch_bounds__(64) void k_pre(
    const float* __restrict__ x, const float* __restrict__ y,
    const float* __restrict__ pw, const float* __restrict__ pb,
    const float* g, const float* bb, const float* m, const float* v,
    const float* lnxg, const float* lnxb,
    const float* lnyg, const float* lnyb,
    const float* lnzg, const float* lnzb,
    float* __restrict__ xl, float* __restrict__ yl, float* __restrict__ zl) {
  __shared__ float xs[64], ys[64];
  int row = blockIdx.x;            // b*N + n
  int c = threadIdx.x;
  int b = row / N_, n = row % N_;
  float xv = x[(size_t)(b * C_ + c) * N_ + n];
  float yv = y[(size_t)(b * C_ + c) * N_ + n];
  xs[c] = xv; ys[c] = yv;
  __syncthreads();
  const float4* wr  = (const float4*)(pw + (size_t)c * 2 * C_);
  const float4* xs4 = (const float4*)xs;
  const float4* ys4 = (const float4*)ys;
  float acc = pb[c];
#pragma unroll
  for (int t = 0; t < 16; ++t) {
    float4 a = xs4[t], wv = wr[t];
    acc += a.x * wv.x + a.y * wv.y + a.z * wv.z + a.w * wv.w;
  }
#pragma unroll
  for (int t = 0; t < 16; ++t) {
    float4 a = ys4[t], wv = wr[16 + t];
    acc += a.x * wv.x + a.y * wv.y + a.z * wv.z + a.w * wv.w;
  }
  float s  = g[c] * rsqrtf(v[c] + EPS_);
  float sh = bb[c] - m[c] * s;
  float tx = xv * s + sh;
  xl[(size_t)row * C_ + c] = ln_val(tx, lnxg[c], lnxb[c]);
  float ty = yv * s + sh;
  yl[(size_t)row * C_ + c] = ln_val(ty, lnyg[c], lnyb[c]);
  float tz = acc * s + sh;
  zl[(size_t)row * C_ + c] = ln_val(tz, lnzg[c], lnzb[c]);
}

// ------------- fused qv (both branches) + k projection --------------------
__global__ void k_qvk(const float* __restrict__ lnb, const float* __restrict__ zl,
                      const float* __restrict__ qvw, const float* __restrict__ qvb,
                      const float* __restrict__ kw, const float* __restrict__ kb,
                      float* __restrict__ qb, float* __restrict__ vb,
                      float* __restrict__ kk) {
  int z = blockIdx.z;
  if (z < 2) {
    int idx = blockIdx.x * 256 + threadIdx.x;   // B*N*128
    int j = idx & 127;
    int row = idx >> 7;
    int b = row / N_, n = row % N_;
    const float4* ir = (const float4*)(lnb + z * S_ + (size_t)row * C_);
    const float4* wr = (const float4*)(qvw + (size_t)j * C_);
    float acc = qvb[j];
#pragma unroll
    for (int t = 0; t < 16; ++t) {
      float4 a = ir[t], wv = wr[t];
      acc += a.x * wv.x + a.y * wv.y + a.z * wv.z + a.w * wv.w;
    }
    int jj = j & 63;
    int h = jj >> 3, d = jj & 7;
    float* dst = ((j < C_) ? qb : vb) + z * 2 * S_;
    dst[((size_t)(b * NH_ + h) * N_ + n) * HD_ + d] = acc;
  } else {
    if (blockIdx.x >= 1152) return;
    int idx = blockIdx.x * 256 + threadIdx.x;   // B*N*64
    int j = idx & 63;
    int row = idx >> 6;
    int b = row / N_, n = row % N_;
    const float4* ir = (const float4*)(zl + (size_t)row * C_);
    const float4* wr = (const float4*)(kw + (size_t)j * C_);
    float acc = kb[j];
#pragma unroll
    for (int t = 0; t < 16; ++t) {
      float4 a = ir[t], wv = wr[t];
      acc += a.x * wv.x + a.y * wv.y + a.z * wv.z + a.w * wv.w;
    }
    int h = j >> 3, d = j & 7;
    kk[((size_t)(b * NH_ + h) * N_ + n) * HD_ + d] = acc;
  }
}

// ---------------- attention v7: 16 waves, no-max, 2-key ILP ---------------
#define AW 16
__global__ __launch_bounds__(1024, 8) void k_attn7(
    const float* __restrict__ xq, const float* __restrict__ xv,
    const float* __restrict__ yq, const float* __restrict__ yv,
    const float* __restrict__ kk,
    float* __restrict__ outx, float* __restrict__ outy) {
  __shared__ float pl[AW][64];
  __shared__ float pbuf[AW][8][64];
  int bh  = blockIdx.y;
  int qt  = blockIdx.x;
  int tid = threadIdx.x;
  int lane = tid & 63;
  int wave = __builtin_amdgcn_readfirstlane(tid >> 6);
  int q = qt * 64 + lane;
  size_t base = (size_t)bh * N_ * HD_;

  float4 qx0 = ((const float4*)(xq + base + (size_t)q * HD_))[0];
  float4 qx1 = ((const float4*)(xq + base + (size_t)q * HD_))[1];
  float4 qy0 = ((const float4*)(yq + base + (size_t)q * HD_))[0];
  float4 qy1 = ((const float4*)(yq + base + (size_t)q * HD_))[1];
  const float fs = S2_ * LOG2E_;
  qx0.x *= fs; qx0.y *= fs; qx0.z *= fs; qx0.w *= fs;
  qx1.x *= fs; qx1.y *= fs; qx1.z *= fs; qx1.w *= fs;

  float l = 0.f;
  float ax[8] = {0,0,0,0,0,0,0,0};
  float ay[8] = {0,0,0,0,0,0,0,0};

  const float4* kp = (const float4*)(kk + base);
  const float4* xp = (const float4*)(xv + base);
  const float4* yp = (const float4*)(yv + base);
  int k0 = wave * (N_ / AW);
  for (int mi = k0; mi < k0 + N_ / AW; mi += 2) {
    float4 kaA  = kp[2 * mi],     kbA = kp[2 * mi + 1];
    float4 kaB  = kp[2 * mi + 2], kbB = kp[2 * mi + 3];
    float4 xaA = xp[2 * mi],     xbA = xp[2 * mi + 1];
    float4 xaB = xp[2 * mi + 2], xbB = xp[2 * mi + 3];
    float4 yaA = yp[2 * mi],     ybA = yp[2 * mi + 1];
    float4 yaB = yp[2 * mi + 2], ybB = yp[2 * mi + 3];
    float s1A = qx0.x*kaA.x + qx0.y*kaA.y + qx0.z*kaA.z + qx0.w*kaA.w
              + qx1.x*kbA.x + qx1.y*kbA.y + qx1.z*kbA.z + qx1.w*kbA.w;
    float s2A = qy0.x*kaA.x + qy0.y*kaA.y + qy0.z*kaA.z + qy0.w*kaA.w
              + qy1.x*kbA.x + qy1.y*kbA.y + qy1.z*kbA.z + qy1.w*kbA.w;
    float s1B = qx0.x*kaB.x + qx0.y*kaB.y + qx0.z*kaB.z + qx0.w*kaB.w
              + qx1.x*kbB.x + qx1.y*kbB.y + qx1.z*kbB.z + qx1.w*kbB.w;
    float s2B = qy0.x*kaB.x + qy0.y*kaB.y + qy0.z*kaB.z + qy0.w*kaB.w
              + qy1.x*kbB.x + qy1.y*kbB.y + qy1.z*kbB.z + qy1.w*kbB.w;
    float pA = exp2f(s1A * s2A);
    float pB = exp2f(s1B * s2B);
    l += pA + pB;
    ax[0] += pA*xaA.x + pB*xaB.x;  ax[1] += pA*xaA.y + pB*xaB.y;
    ax[2] += pA*xaA.z + pB*xaB.z;  ax[3] += pA*xaA.w + pB*xaB.w;
    ax[4] += pA*xbA.x + pB*xbB.x;  ax[5] += pA*xbA.y + pB*xbB.y;
    ax[6] += pA*xbA.z + pB*xbB.z;  ax[7] += pA*xbA.w + pB*xbB.w;
    ay[0] += pA*yaA.x + pB*yaB.x;  ay[1] += pA*yaA.y + pB*yaB.y;
    ay[2] += pA*yaA.z + pB*yaB.z;  ay[3] += pA*yaA.w + pB*yaB.w;
    ay[4] += pA*ybA.x + pB*ybB.x;  ay[5] += pA*ybA.y + pB*ybB.y;
    ay[6] += pA*ybA.z + pB*ybB.z;  ay[7] += pA*ybA.w + pB*ybB.w;
  }
  pl[wave][lane] = l;
#pragma unroll
  for (int d = 0; d < 8; ++d) pbuf[wave][d][lane] = ax[d];
  __syncthreads();
  float Linv = 0.f;
  int b = bh / NH_, h = bh % NH_;
  if (tid < 64) {
    float L = 0.f;
#pragma unroll
    for (int w = 0; w < AW; ++w) L += pl[w][lane];
    Linv = 1.f / L;
    float A[8] = {0,0,0,0,0,0,0,0};
#pragma unroll
    for (int w = 0; w < AW; ++w)
#pragma unroll
      for (int d = 0; d < 8; ++d) A[d] += pbuf[w][d][lane];
    float* o = outx + ((size_t)(b * N_ + q)) * C_ + h * HD_;
#pragma unroll
    for (int d = 0; d < 8; ++d) o[d] = A[d] * Linv;
  }
  __syncthreads();
#pragma unroll
  for (int d = 0; d < 8; ++d) pbuf[wave][d][lane] = ay[d];
  __syncthreads();
  if (tid < 64) {
    float A[8] = {0,0,0,0,0,0,0,0};
#pragma unroll
    for (int w = 0; w < AW; ++w)
#pragma unroll
      for (int d = 0; d < 8; ++d) A[d] += pbuf[w][d][lane];
    float* o = outy + ((size_t)(b * N_ + q)) * C_ + h * HD_;
#pragma unroll
    for (int d = 0; d < 8; ++d) o[d] = A[d] * Linv;
  }
}

// -------- proj + recomputed-BN residual, 2 px/thread ----------------------
// grid (18, C_, 2*B_), block 64. out layout z*CN, z = branch*B_ + b.
__global__ __launch_bounds__(64) void k_proj2(
    const float* __restrict__ attbase,
    const float* __restrict__ x, const float* __restrict__ y,
    const float* bg, const float* bb2, const float* bm, const float* bv,
    const float* __restrict__ pw, const float* __restrict__ pbias,
    float* __restrict__ outbase) {
  int p = blockIdx.x * 128 + threadIdx.x * 2;
  int c = blockIdx.y;
  int z = blockIdx.z;
  int branch = z >> 1, b = z & 1;
  const float* att = attbase + branch * S_ + (size_t)b * N_ * C_;
  const float4* wr = (const float4*)(pw + (size_t)c * C_);
  float bias = pbias[c];
  float acc[2];
#pragma unroll
  for (int i = 0; i < 2; ++i) {
    const float4* ar = (const float4*)(att + (size_t)(p + i) * C_);
    float a = bias;
#pragma unroll
    for (int t = 0; t < 16; ++t) {
      float4 av = ar[t], wv = wr[t];
      a += av.x * wv.x + av.y * wv.y + av.z * wv.z + av.w * wv.w;
    }
    acc[i] = a;
  }
  float s  = bg[c] * rsqrtf(bv[c] + EPS_);
  float sh = bb2[c] - bm[c] * s;
  const float* xin = branch ? y : x;
  float2 r = *(const float2*)(xin + ((size_t)b * C_ + c) * N_ + p);
  size_t o = (size_t)z * CN_ + (size_t)c * N_ + p;
  *(float2*)(outbase + o) = make_float2(acc[0] + r.x * s + sh,
                                        acc[1] + r.y * s + sh);
}

// ------ 64-cin conv RAW partial: cin half, 2 couts + 2 px -----------------
// grid (18, C_/2, 8), block 64. z: img = z&3 (layout img*CN), half = z>>2.
// half0 -> pA + img*CN, half1 -> pB + img*CN.
__global__ __launch_bounds__(64) void k_convs(
    const float* __restrict__ inA, const float* __restrict__ inB,
    const float* __restrict__ w,
    float* __restrict__ pA, float* __restrict__ pB) {
  int p = blockIdx.x * 128 + threadIdx.x * 2;
  int c0 = blockIdx.y * 2;
  int z = blockIdx.z;
  int img = z & 3, half = z >> 2;
  int yy = p / W_, x0 = p % W_;
  const float* ib = (img < 2) ? inA + (size_t)img * CN_
                              : inB + (size_t)(img - 2) * CN_;
  const float* w0r = w + (size_t)c0 * C_ * 9;
  const float* w1r = w0r + (size_t)C_ * 9;
  float a00 = 0.f, a01 = 0.f, a10 = 0.f, a11 = 0.f;
  int ci0 = half * (C_ / 2);
#pragma unroll 4
  for (int ci = ci0; ci < ci0 + C_ / 2; ++ci) {
    const float* ip = ib + ci * N_;
    const float* wp0 = w0r + ci * 9;
    const float* wp1 = w1r + ci * 9;
#pragma unroll
    for (int ky = 0; ky < 3; ++ky) {
      int iyy = yy + ky - 1;
      if ((unsigned)iyy >= (unsigned)H_) continue;
      const float* rp = ip + iyy * W_;
      float2 mid = *(const float2*)(rp + x0);
      float vL = (x0 > 0) ? rp[x0 - 1] : 0.f;
      float vR = (x0 + 2 < W_) ? rp[x0 + 2] : 0.f;
      float u0 = wp0[ky*3], u1 = wp0[ky*3+1], u2 = wp0[ky*3+2];
      float t0 = wp1[ky*3], t1 = wp1[ky*3+1], t2 = wp1[ky*3+2];
      a00 += vL*u0 + mid.x*u1 + mid.y*u2;
      a01 += mid.x*u0 + mid.y*u1 + vR*u2;
      a10 += vL*t0 + mid.x*t1 + mid.y*t2;
      a11 += mid.x*t0 + mid.y*t1 + vR*t2;
    }
  }
  float* ob = (half ? pB : pA) + (size_t)img * CN_ + (size_t)c0 * N_ + p;
  *(float2*)(ob)      = make_float2(a00, a01);
  *(float2*)(ob + N_) = make_float2(a10, a11);
}

// ------ combine halves + bias + bn + relu (conv1 epilogue) ----------------
// grid 576, block 256. 4 images x CN. tmp: img<2 -> tA+img*CN else tB+(img-2)*CN
__global__ void k_combp(const float* __restrict__ pA, const float* __restrict__ pB,
                        const float* __restrict__ cb,
                        const float* __restrict__ g, const float* __restrict__ b2,
                        const float* __restrict__ m, const float* __restrict__ v,
                        float* __restrict__ tA, float* __restrict__ tB) {
  int t = blockIdx.x * 256 + threadIdx.x;
  int p4 = t * 4;
  int n = p4 % N_;
  int c = (p4 / N_) % C_;
  int img = p4 / (int)CN_;
  size_t off = (size_t)img * CN_ + (size_t)c * N_ + n;
  float4 a = *(const float4*)(pA + off);
  float4 d = *(const float4*)(pB + off);
  float s  = g[c] * rsqrtf(v[c] + EPS_);
  float sh = b2[c] - m[c] * s;
  float bias = cb[c];
  float4 r;
  r.x = fmaxf((a.x + d.x + bias) * s + sh, 0.f);
  r.y = fmaxf((a.y + d.y + bias) * s + sh, 0.f);
  r.z = fmaxf((a.z + d.z + bias) * s + sh, 0.f);
  r.w = fmaxf((a.w + d.w + bias) * s + sh, 0.f);
  float* ob = (img < 2) ? tA + off : tB + off - 2 * CN_;
  *(float4*)ob = r;
}

// ------ combine halves + bias + bn + relu + resid (conv2 epilogue) --------
// grid 576, block 256. writes o2 into pA in place (layout img*CN).
__global__ void k_comb2(float* __restrict__ pA, const float* __restrict__ pB,
                        const float* __restrict__ cb,
                        const float* __restrict__ g, const float* __restrict__ b2,
                        const float* __restrict__ m, const float* __restrict__ v,
                        const float* __restrict__ resid) {
  int t = blockIdx.x * 256 + threadIdx.x;
  int p4 = t * 4;
  int n = p4 % N_;
  int c = (p4 / N_) % C_;
  int img = p4 / (int)CN_;
  size_t off = (size_t)img * CN_ + (size_t)c * N_ + n;
  float4 a = *(const float4*)(pA + off);
  float4 d = *(const float4*)(pB + off);
  float4 rr = *(const float4*)(resid + off);
  float s  = g[c] * rsqrtf(v[c] + EPS_);
  float sh = b2[c] - m[c] * s;
  float bias = cb[c];
  float4 r;
  r.x = fmaxf((a.x + d.x + bias) * s + sh, 0.f) + rr.x;
  r.y = fmaxf((a.y + d.y + bias) * s + sh, 0.f) + rr.y;
  r.z = fmaxf((a.z + d.z + bias) * s + sh, 0.f) + rr.z;
  r.w = fmaxf((a.w + d.w + bias) * s + sh, 0.f) + rr.w;
  *(float4*)(pA + off) = r;
}

// ------ cat = [xo+yo ; xo*yo] + bn2 -> fin, float4 ------------------------
// grid 576, block 256. o2 layout img*CN (x: img=b, y: img=2+b).
__global__ void k_catbn(const float* __restrict__ o2,
                        const float* __restrict__ g, const float* __restrict__ b2,
                        const float* __restrict__ m, const float* __restrict__ v,
                        float* __restrict__ cat, float* __restrict__ fin,
                        size_t finStride) {
  int t = blockIdx.x * 256 + threadIdx.x;
  int p4 = t * 4;
  int n  = p4 % N_;
  int c2 = (p4 / N_) % (2 * C_);
  int b  = p4 / (2 * C_ * N_);
  int c  = c2 & 63;
  float4 X = *(const float4*)(o2 + (size_t)b * CN_ + (size_t)c * N_ + n);
  float4 Y = *(const float4*)(o2 + (size_t)(2 + b) * CN_ + (size_t)c * N_ + n);
  float4 val;
  if (c2 < C_) val = make_float4(X.x + Y.x, X.y + Y.y, X.z + Y.z, X.w + Y.w);
  else         val = make_float4(X.x * Y.x, X.y * Y.y, X.z * Y.z, X.w * Y.w);
  size_t co = ((size_t)b * 2 * C_ + c2) * N_ + n;
  *(float4*)(cat + co) = val;
  float s  = g[c2] * rsqrtf(v[c2] + EPS_);
  float sh = b2[c2] - m[c2] * s;
  *(float4*)(fin + (size_t)b * finStride + (size_t)c2 * N_ + n) =
      make_float4(val.x * s + sh, val.y * s + sh, val.z * s + sh, val.w * s + sh);
}

// ------ f-branch 3x3 conv partial (64-cin half), 2 couts + 2 px -----------
// grid (18, C_, 2*B_), block 64. z: b = z&1, half = z>>1.
__global__ __launch_bounds__(64) void k_fconvs(
    const float* __restrict__ in, size_t inStride,
    const float* __restrict__ w,
    float* __restrict__ outA, size_t outStrideA,
    float* __restrict__ outB, size_t outStrideB) {
  int p = blockIdx.x * 128 + threadIdx.x * 2;
  int c0 = blockIdx.y * 2;
  int z = blockIdx.z;
  int b = z & 1, half = z >> 1;
  int yy = p / W_, x0 = p % W_;
  const float* ib = in + (size_t)b * inStride;
  const float* w0r = w + (size_t)c0 * (2 * C_) * 9;
  const float* w1r = w0r + (size_t)(2 * C_) * 9;
  float a00 = 0.f, a01 = 0.f, a10 = 0.f, a11 = 0.f;
  int ci0 = half * C_;
#pragma unroll 4
  for (int ci = ci0; ci < ci0 + C_; ++ci) {
    const float* ip = ib + ci * N_;
    const float* wp0 = w0r + ci * 9;
    const float* wp1 = w1r + ci * 9;
#pragma unroll
    for (int ky = 0; ky < 3; ++ky) {
      int iyy = yy + ky - 1;
      if ((unsigned)iyy >= (unsigned)H_) continue;
      const float* rp = ip + iyy * W_;
      float2 mid = *(const float2*)(rp + x0);
      float vL = (x0 > 0) ? rp[x0 - 1] : 0.f;
      float vR = (x0 + 2 < W_) ? rp[x0 + 2] : 0.f;
      float u0 = wp0[ky*3], u1 = wp0[ky*3+1], u2 = wp0[ky*3+2];
      float t0 = wp1[ky*3], t1 = wp1[ky*3+1], t2 = wp1[ky*3+2];
      a00 += vL*u0 + mid.x*u1 + mid.y*u2;
      a01 += mid.x*u0 + mid.y*u1 + vR*u2;
      a10 += vL*t0 + mid.x*t1 + mid.y*t2;
      a11 += mid.x*t0 + mid.y*t1 + vR*t2;
    }
  }
  float* ob = (half ? outB + (size_t)b * outStrideB
                    : outA + (size_t)b * outStrideA);
  size_t o = (size_t)c0 * N_ + p;
  *(float2*)(ob + o)      = make_float2(a00, a01);
  *(float2*)(ob + o + N_) = make_float2(a10, a11);
}

// ------ combine halves + bn + relu, float4 (in-place into A ok) -----------
__global__ void k_comb(const float* __restrict__ pA, size_t strideA,
                       const float* __restrict__ pB, size_t strideB,
                       const float* __restrict__ g, const float* __restrict__ b2,
                       const float* __restrict__ m, const float* __restrict__ v,
                       float* __restrict__ out, size_t outStride) {
  int t = blockIdx.x * 256 + threadIdx.x;
  int p4 = t * 4;
  int n = p4 % N_;
  int c = (p4 / N_) % (2 * C_);
  int b = p4 / (2 * C_ * N_);
  size_t off = (size_t)c * N_ + n;
  float4 a = *(const float4*)(pA + (size_t)b * strideA + off);
  float4 d = *(const float4*)(pB + (size_t)b * strideB + off);
  float s  = g[c] * rsqrtf(v[c] + EPS_);
  float sh = b2[c] - m[c] * s;
  float4 r;
  r.x = fmaxf((a.x + d.x) * s + sh, 0.f);
  r.y = fmaxf((a.y + d.y) * s + sh, 0.f);
  r.z = fmaxf((a.z + d.z) * s + sh, 0.f);
  r.w = fmaxf((a.w + d.w) * s + sh, 0.f);
  *(float4*)(out + (size_t)b * outStride + off) = r;
}

// -------- final 1x1 conv over fused comb(pA,pB)+bn+relu, + cat add --------
// grid (18, 2C, B), block 64. bn scale/shift precomputed into LDS.
__global__ __launch_bounds__(64) void k_final3(
    const float* __restrict__ pA, size_t strideA,
    const float* __restrict__ pB, size_t strideB,
    const float* __restrict__ g2, const float* __restrict__ b2,
    const float* __restrict__ m2, const float* __restrict__ v2,
    const float* __restrict__ cat,
    const float* __restrict__ w, const float* __restrict__ fb,
    float* __restrict__ out) {
  __shared__ float fsc[2 * C_], fsh[2 * C_];
  for (int j = threadIdx.x; j < 2 * C_; j += 64) {
    float s = g2[j] * rsqrtf(v2[j] + EPS_);
    fsc[j] = s;
    fsh[j] = b2[j] - m2[j] * s;
  }
  __syncthreads();
  int p = blockIdx.x * 128 + threadIdx.x * 2;
  int c = blockIdx.y, b = blockIdx.z;
  const float* frA = pA + (size_t)b * strideA;
  const float* frB = pB + (size_t)b * strideB;
  const float* wr = w + (size_t)c * 2 * C_;
  float a0 = fb[c], a1 = a0;
  for (int j = 0; j < 2 * C_; ++j) {
    float2 fa = *(const float2*)(frA + (size_t)j * N_ + p);
    float2 fd = *(const float2*)(frB + (size_t)j * N_ + p);
    float s = fsc[j], sh = fsh[j];
    float f0 = fmaxf((fa.x + fd.x) * s + sh, 0.f);
    float f1 = fmaxf((fa.y + fd.y) * s + sh, 0.f);
    float wv = wr[j];
    a0 += wv * f0; a1 += wv * f1;
  }
  size_t o = ((size_t)b * 2 * C_ + c) * N_ + p;
  float2 cv = *(const float2*)(cat + o);
  *(float2*)(out + o) = make_float2(a0 + cv.x, a1 + cv.y);
}

extern "C" void kernel_launch(void* const* d_in, const int* in_sizes, int n_in,
                              void* d_out, int out_size, void* d_ws, size_t ws_size,
                              hipStream_t stream) {
  const float* x       = (const float*)d_in[0];
  const float* y       = (const float*)d_in[1];
  const float* pconv_w = (const float*)d_in[2];
  const float* pconv_b = (const float*)d_in[3];
  const float* bnd_g = (const float*)d_in[4];
  const float* bnd_b = (const float*)d_in[5];
  const float* bnd_m = (const float*)d_in[6];
  const float* bnd_v = (const float*)d_in[7];
  const float* lnx_g = (const float*)d_in[8];
  const float* lnx_b = (const float*)d_in[9];
  const float* lny_g = (const float*)d_in[10];
  const float* lny_b = (const float*)d_in[11];
  const float* lnz_g = (const float*)d_in[12];
  const float* lnz_b = (const float*)d_in[13];
  const float* k_w   = (const float*)d_in[14];
  const float* k_b   = (const float*)d_in[15];
  const float* qv_w  = (const float*)d_in[16];
  const float* qv_b  = (const float*)d_in[17];
  const float* proj_w = (const float*)d_in[18];
  const float* proj_b = (const float*)d_in[19];
  const float* c2w1  = (const float*)d_in[20];
  const float* c2b1  = (const float*)d_in[21];
  const float* c2bn1_g = (const float*)d_in[22];
  const float* c2bn1_b = (const float*)d_in[23];
  const float* c2bn1_m = (const float*)d_in[24];
  const float* c2bn1_v = (const float*)d_in[25];
  const float* c2w2  = (const float*)d_in[26];
  const float* c2b2  = (const float*)d_in[27];
  const float* c2bn2_g = (const float*)d_in[28];
  const float* c2bn2_b = (const float*)d_in[29];
  const float* c2bn2_m = (const float*)d_in[30];
  const float* c2bn2_v = (const float*)d_in[31];
  const float* bn2_g = (const float*)d_in[32];
  const float* bn2_b = (const float*)d_in[33];
  const float* bn2_m = (const float*)d_in[34];
  const float* bn2_v = (const float*)d_in[35];
  const float* f1w   = (const float*)d_in[36];
  const float* fbn1_g = (const float*)d_in[37];
  const float* fbn1_b = (const float*)d_in[38];
  const float* fbn1_m = (const float*)d_in[39];
  const float* fbn1_v = (const float*)d_in[40];
  const float* f2w   = (const float*)d_in[41];
  const float* fbn2_g = (const float*)d_in[42];
  const float* fbn2_b = (const float*)d_in[43];
  const float* fbn2_m = (const float*)d_in[44];
  const float* fbn2_v = (const float*)d_in[45];
  const float* f3w   = (const float*)d_in[46];
  const float* f3b   = (const float*)d_in[47];

  // 8-slot workspace plan:
  //   A: k_pre -> xl(1) yl(2) zl(3)
  //   B: qvk -> xq(4) xv(5) yq(6) yv(7); kk(0)
  //   C: attn7 -> att_xo(1) att_yo(2)
  //   D: proj -> xo4(3,4) [img*CN, imgs 0..3]
  //   E1: convs(conv1) raw partials: half0 -> (1,2), half1 -> (5,6)
  //   E2: combp (+bias/bn/relu) -> tmp imgs01 (0), imgs23 (7)
  //   F1: convs(conv2) raw partials from tmp -> (1,2)(5,6)
  //   F2: comb2 (+bias/bn/relu + resid(3,4)) -> o2 in-place (1,2)
  //   G: catbn reads o2(1,2) -> cat(3,4), fin b0->(0), b1->(7) [stride 7S]
  //   H1: fconvs f1: fin(0/7) -> half0 (1,2 stride S), half1 (5,6 stride S)
  //   H2: comb -> (1,2) in-place
  //   H3: fconvs f2: (1,2) -> half0 (5,6), half1 (0/7)
  //   I: final3 reads (5,6)+(0/7), cat(3,4) -> out
  float* ws = (float*)d_ws;
  float* sl0 = ws + 0 * S_;
  float* sl1 = ws + 1 * S_;
  float* sl2 = ws + 2 * S_;
  float* sl3 = ws + 3 * S_;
  float* sl4 = ws + 4 * S_;
  float* sl5 = ws + 5 * S_;
  float* sl7 = ws + 7 * S_;

  // A. fused pconv + bn + ln
  k_pre<<<B_ * N_, 64, 0, stream>>>(x, y, pconv_w, pconv_b,
                                    bnd_g, bnd_b, bnd_m, bnd_v,
                                    lnx_g, lnx_b, lny_g, lny_b, lnz_g, lnz_b,
                                    sl1, sl2, sl3);
  // B. fused qv + kproj
  {
    dim3 g(2304, 1, 3);
    k_qvk<<<g, 256, 0, stream>>>(sl1, sl3, qv_w, qv_b, k_w, k_b, sl4, sl5, sl0);
  }
  // C. attention v7 -> att_xo(1), att_yo(2)
  {
    dim3 g(N_ / 64, B_ * NH_);
    k_attn7<<<g, 1024, 0, stream>>>(sl4, sl5, ws + 6 * S_, ws + 7 * S_, sl0,
                                    sl1, sl2);
  }
  // D. proj batched -> xo4(3,4)
  {
    dim3 g(18, C_, 2 * B_);
    k_proj2<<<g, 64, 0, stream>>>(sl1, x, y, bnd_g, bnd_b, bnd_m, bnd_v,
                                  proj_w, proj_b, sl3);
  }
  // E. conv1: cin-split raw partials + combine epilogue -> tmp(0 / 7)
  {
    dim3 g(18, C_ / 2, 8);
    k_convs<<<g, 64, 0, stream>>>(sl3, sl3 + 2 * CN_, c2w1, sl1, sl5);
    k_combp<<<576, 256, 0, stream>>>(sl1, sl5, c2b1,
        c2bn1_g, c2bn1_b, c2bn1_m, c2bn1_v, sl0, sl7);
  }
  // F. conv2: cin-split raw partials + combine(+resid) -> o2(1,2)
  {
    dim3 g(18, C_ / 2, 8);
    k_convs<<<g, 64, 0, stream>>>(sl0, sl7, c2w2, sl1, sl5);
    k_comb2<<<576, 256, 0, stream>>>(sl1, sl5, c2b2,
        c2bn2_g, c2bn2_b, c2bn2_m, c2bn2_v, sl3);
  }
  // G. cat + bn2 -> cat(3,4), fin(0 / 7)
  k_catbn<<<576, 256, 0, stream>>>(sl1, bn2_g, bn2_b, bn2_m, bn2_v,
                                   sl3, sl0, 7 * S_);
  // H. f-branch convs, ci-split, 2 px/thread
  {
    dim3 g(18, C_, 2 * B_);
    k_fconvs<<<g, 64, 0, stream>>>(sl0, 7 * S_, f1w, sl1, S_, sl5, S_);
    k_comb<<<576, 256, 0, stream>>>(sl1, S_, sl5, S_,
                                    fbn1_g, fbn1_b, fbn1_m, fbn1_v, sl1, S_);
    k_fconvs<<<g, 64, 0, stream>>>(sl1, S_, f2w, sl5, S_, sl0, 7 * S_);
  }
  // I. final 1x1 fused with comb(fbn2) + cat add -> fp32 out
  {
    dim3 g(18, 2 * C_, B_);
    k_final3<<<g, 64, 0, stream>>>(sl5, S_, sl0, 7 * S_,
                                   fbn2_g, fbn2_b, fbn2_m, fbn2_v,
                                   sl3, f3w, f3b, (float*)d_out);
  }
}

// Round 16
// 650.860 us; speedup vs baseline: 1.1319x; 1.0062x over previous
//
#include <hip/hip_runtime.h>
#include <hip/hip_bf16.h>

#define B_   2
#define C_   64
#define H_   48
#define W_   48
#define N_   (H_*W_)     // 2304
#define NH_  8
#define HD_  8
#define EPS_ 1e-5f
#define S2_  0.125f      // scale^2 = 1/hd
#define LOG2E_ 1.44269504f
#define S_   ((size_t)B_ * C_ * N_)   // 294912 floats per workspace slot
#define CN_  ((size_t)C_ * N_)        // 147456 floats per image

__device__ __forceinline__ float wsum64(float v) {
#pragma unroll
  for (int o = 32; o > 0; o >>= 1) v += __shfl_xor(v, o, 64);
  return v;
}

__device__ __forceinline__ float ln_val(float t, float g, float b) {
  float mu  = wsum64(t) * (1.0f / 64.0f);
  float d   = t - mu;
  float var = wsum64(d * d) * (1.0f / 64.0f);
  return d * rsqrtf(var + EPS_) * g + b;
}

// ---- fused 1x1 pconv + BN + 3x LayerNorm; block = one (b,n) row ----------
__global__ __launch_bounds__(64) void k_pre(
    const float* __restrict__ x, const float* __restrict__ y,
    const float* __restrict__ pw, const float* __restrict__ pb,
    const float* g, const float* bb, const float* m, const float* v,
    const float* lnxg, const float* lnxb,
    const float* lnyg, const float* lnyb,
    const float* lnzg, const float* lnzb,
    float* __restrict__ xl, float* __restrict__ yl, float* __restrict__ zl) {
  __shared__ float xs[64], ys[64];
  int row = blockIdx.x;            // b*N + n
  int c = threadIdx.x;
  int b = row / N_, n = row % N_;
  float xv = x[(size_t)(b * C_ + c) * N_ + n];
  float yv = y[(size_t)(b * C_ + c) * N_ + n];
  xs[c] = xv; ys[c] = yv;
  __syncthreads();
  const float4* wr  = (const float4*)(pw + (size_t)c * 2 * C_);
  const float4* xs4 = (const float4*)xs;
  const float4* ys4 = (const float4*)ys;
  float acc = pb[c];
#pragma unroll
  for (int t = 0; t < 16; ++t) {
    float4 a = xs4[t], wv = wr[t];
    acc += a.x * wv.x + a.y * wv.y + a.z * wv.z + a.w * wv.w;
  }
#pragma unroll
  for (int t = 0; t < 16; ++t) {
    float4 a = ys4[t], wv = wr[16 + t];
    acc += a.x * wv.x + a.y * wv.y + a.z * wv.z + a.w * wv.w;
  }
  float s  = g[c] * rsqrtf(v[c] + EPS_);
  float sh = bb[c] - m[c] * s;
  float tx = xv * s + sh;
  xl[(size_t)row * C_ + c] = ln_val(tx, lnxg[c], lnxb[c]);
  float ty = yv * s + sh;
  yl[(size_t)row * C_ + c] = ln_val(ty, lnyg[c], lnyb[c]);
  float tz = acc * s + sh;
  zl[(size_t)row * C_ + c] = ln_val(tz, lnzg[c], lnzb[c]);
}

// ------------- fused qv (both branches) + k projection --------------------
__global__ void k_qvk(const float* __restrict__ lnb, const float* __restrict__ zl,
                      const float* __restrict__ qvw, const float* __restrict__ qvb,
                      const float* __restrict__ kw, const float* __restrict__ kb,
                      float* __restrict__ qb, float* __restrict__ vb,
                      float* __restrict__ kk) {
  int z = blockIdx.z;
  if (z < 2) {
    int idx = blockIdx.x * 256 + threadIdx.x;   // B*N*128
    int j = idx & 127;
    int row = idx >> 7;
    int b = row / N_, n = row % N_;
    const float4* ir = (const float4*)(lnb + z * S_ + (size_t)row * C_);
    const float4* wr = (const float4*)(qvw + (size_t)j * C_);
    float acc = qvb[j];
#pragma unroll
    for (int t = 0; t < 16; ++t) {
      float4 a = ir[t], wv = wr[t];
      acc += a.x * wv.x + a.y * wv.y + a.z * wv.z + a.w * wv.w;
    }
    int jj = j & 63;
    int h = jj >> 3, d = jj & 7;
    float* dst = ((j < C_) ? qb : vb) + z * 2 * S_;
    dst[((size_t)(b * NH_ + h) * N_ + n) * HD_ + d] = acc;
  } else {
    if (blockIdx.x >= 1152) return;
    int idx = blockIdx.x * 256 + threadIdx.x;   // B*N*64
    int j = idx & 63;
    int row = idx >> 6;
    int b = row / N_, n = row % N_;
    const float4* ir = (const float4*)(zl + (size_t)row * C_);
    const float4* wr = (const float4*)(kw + (size_t)j * C_);
    float acc = kb[j];
#pragma unroll
    for (int t = 0; t < 16; ++t) {
      float4 a = ir[t], wv = wr[t];
      acc += a.x * wv.x + a.y * wv.y + a.z * wv.z + a.w * wv.w;
    }
    int h = j >> 3, d = j & 7;
    kk[((size_t)(b * NH_ + h) * N_ + n) * HD_ + d] = acc;
  }
}

// -------- attention v8: 16 waves, no-max, 2-key ILP, parallel merge -------
#define AW 16
__global__ __launch_bounds__(1024, 8) void k_attn8(
    const float* __restrict__ xq, const float* __restrict__ xv,
    const float* __restrict__ yq, const float* __restrict__ yv,
    const float* __restrict__ kk,
    float* __restrict__ outx, float* __restrict__ outy) {
  __shared__ float pl[AW][64];
  __shared__ float pbuf[AW][8][64];
  int bh  = blockIdx.y;
  int qt  = blockIdx.x;
  int tid = threadIdx.x;
  int lane = tid & 63;
  int wave = __builtin_amdgcn_readfirstlane(tid >> 6);
  int q = qt * 64 + lane;
  size_t base = (size_t)bh * N_ * HD_;

  float4 qx0 = ((const float4*)(xq + base + (size_t)q * HD_))[0];
  float4 qx1 = ((const float4*)(xq + base + (size_t)q * HD_))[1];
  float4 qy0 = ((const float4*)(yq + base + (size_t)q * HD_))[0];
  float4 qy1 = ((const float4*)(yq + base + (size_t)q * HD_))[1];
  const float fs = S2_ * LOG2E_;
  qx0.x *= fs; qx0.y *= fs; qx0.z *= fs; qx0.w *= fs;
  qx1.x *= fs; qx1.y *= fs; qx1.z *= fs; qx1.w *= fs;

  float l = 0.f;
  float ax[8] = {0,0,0,0,0,0,0,0};
  float ay[8] = {0,0,0,0,0,0,0,0};

  const float4* kp = (const float4*)(kk + base);
  const float4* xp = (const float4*)(xv + base);
  const float4* yp = (const float4*)(yv + base);
  int k0 = wave * (N_ / AW);
  for (int mi = k0; mi < k0 + N_ / AW; mi += 2) {
    float4 kaA  = kp[2 * mi],     kbA = kp[2 * mi + 1];
    float4 kaB  = kp[2 * mi + 2], kbB = kp[2 * mi + 3];
    float4 xaA = xp[2 * mi],     xbA = xp[2 * mi + 1];
    float4 xaB = xp[2 * mi + 2], xbB = xp[2 * mi + 3];
    float4 yaA = yp[2 * mi],     ybA = yp[2 * mi + 1];
    float4 yaB = yp[2 * mi + 2], ybB = yp[2 * mi + 3];
    float s1A = qx0.x*kaA.x + qx0.y*kaA.y + qx0.z*kaA.z + qx0.w*kaA.w
              + qx1.x*kbA.x + qx1.y*kbA.y + qx1.z*kbA.z + qx1.w*kbA.w;
    float s2A = qy0.x*kaA.x + qy0.y*kaA.y + qy0.z*kaA.z + qy0.w*kaA.w
              + qy1.x*kbA.x + qy1.y*kbA.y + qy1.z*kbA.z + qy1.w*kbA.w;
    float s1B = qx0.x*kaB.x + qx0.y*kaB.y + qx0.z*kaB.z + qx0.w*kaB.w
              + qx1.x*kbB.x + qx1.y*kbB.y + qx1.z*kbB.z + qx1.w*kbB.w;
    float s2B = qy0.x*kaB.x + qy0.y*kaB.y + qy0.z*kaB.z + qy0.w*kaB.w
              + qy1.x*kbB.x + qy1.y*kbB.y + qy1.z*kbB.z + qy1.w*kbB.w;
    float pA = exp2f(s1A * s2A);
    float pB = exp2f(s1B * s2B);
    l += pA + pB;
    ax[0] += pA*xaA.x + pB*xaB.x;  ax[1] += pA*xaA.y + pB*xaB.y;
    ax[2] += pA*xaA.z + pB*xaB.z;  ax[3] += pA*xaA.w + pB*xaB.w;
    ax[4] += pA*xbA.x + pB*xbB.x;  ax[5] += pA*xbA.y + pB*xbB.y;
    ax[6] += pA*xbA.z + pB*xbB.z;  ax[7] += pA*xbA.w + pB*xbB.w;
    ay[0] += pA*yaA.x + pB*yaB.x;  ay[1] += pA*yaA.y + pB*yaB.y;
    ay[2] += pA*yaA.z + pB*yaB.z;  ay[3] += pA*yaA.w + pB*yaB.w;
    ay[4] += pA*ybA.x + pB*ybB.x;  ay[5] += pA*ybA.y + pB*ybB.y;
    ay[6] += pA*ybA.z + pB*ybB.z;  ay[7] += pA*ybA.w + pB*ybB.w;
  }
  pl[wave][lane] = l;
#pragma unroll
  for (int d = 0; d < 8; ++d) pbuf[wave][d][lane] = ax[d];
  __syncthreads();
  int b = bh / NH_, h = bh % NH_;
  // phase 1: 8 waves merge ax (thread = (d, lane))
  if (tid < 512) {
    int d = tid >> 6, ln = tid & 63;
    float L = 0.f;
#pragma unroll
    for (int w = 0; w < AW; ++w) L += pl[w][ln];
    float A = 0.f;
#pragma unroll
    for (int w = 0; w < AW; ++w) A += pbuf[w][d][ln];
    outx[((size_t)(b * N_ + qt * 64 + ln)) * C_ + h * HD_ + d] = A * (1.f / L);
  }
  __syncthreads();
#pragma unroll
  for (int d = 0; d < 8; ++d) pbuf[wave][d][lane] = ay[d];
  __syncthreads();
  // phase 2: 8 waves merge ay
  if (tid < 512) {
    int d = tid >> 6, ln = tid & 63;
    float L = 0.f;
#pragma unroll
    for (int w = 0; w < AW; ++w) L += pl[w][ln];
    float A = 0.f;
#pragma unroll
    for (int w = 0; w < AW; ++w) A += pbuf[w][d][ln];
    outy[((size_t)(b * N_ + qt * 64 + ln)) * C_ + h * HD_ + d] = A * (1.f / L);
  }
}

// -------- proj + recomputed-BN residual, 2 px/thread ----------------------
// grid (18, C_, 2*B_), block 64. out layout z*CN, z = branch*B_ + b.
__global__ __launch_bounds__(64) void k_proj2(
    const float* __restrict__ attbase,
    const float* __restrict__ x, const float* __restrict__ y,
    const float* bg, const float* bb2, const float* bm, const float* bv,
    const float* __restrict__ pw, const float* __restrict__ pbias,
    float* __restrict__ outbase) {
  int p = blockIdx.x * 128 + threadIdx.x * 2;
  int c = blockIdx.y;
  int z = blockIdx.z;
  int branch = z >> 1, b = z & 1;
  const float* att = attbase + branch * S_ + (size_t)b * N_ * C_;
  const float4* wr = (const float4*)(pw + (size_t)c * C_);
  float bias = pbias[c];
  float acc[2];
#pragma unroll
  for (int i = 0; i < 2; ++i) {
    const float4* ar = (const float4*)(att + (size_t)(p + i) * C_);
    float a = bias;
#pragma unroll
    for (int t = 0; t < 16; ++t) {
      float4 av = ar[t], wv = wr[t];
      a += av.x * wv.x + av.y * wv.y + av.z * wv.z + av.w * wv.w;
    }
    acc[i] = a;
  }
  float s  = bg[c] * rsqrtf(bv[c] + EPS_);
  float sh = bb2[c] - bm[c] * s;
  const float* xin = branch ? y : x;
  float2 r = *(const float2*)(xin + ((size_t)b * C_ + c) * N_ + p);
  size_t o = (size_t)z * CN_ + (size_t)c * N_ + p;
  *(float2*)(outbase + o) = make_float2(acc[0] + r.x * s + sh,
                                        acc[1] + r.y * s + sh);
}

// ------ 64-cin conv RAW partial: cin half, 2 couts + 2 px -----------------
// grid (18, C_/2, 8), block 64. z: img = z&3 (layout img*CN), half = z>>2.
__global__ __launch_bounds__(64) void k_convs(
    const float* __restrict__ inA, const float* __restrict__ inB,
    const float* __restrict__ w,
    float* __restrict__ pA, float* __restrict__ pB) {
  int p = blockIdx.x * 128 + threadIdx.x * 2;
  int c0 = blockIdx.y * 2;
  int z = blockIdx.z;
  int img = z & 3, half = z >> 2;
  int yy = p / W_, x0 = p % W_;
  const float* ib = (img < 2) ? inA + (size_t)img * CN_
                              : inB + (size_t)(img - 2) * CN_;
  const float* w0r = w + (size_t)c0 * C_ * 9;
  const float* w1r = w0r + (size_t)C_ * 9;
  float a00 = 0.f, a01 = 0.f, a10 = 0.f, a11 = 0.f;
  int ci0 = half * (C_ / 2);
#pragma unroll 4
  for (int ci = ci0; ci < ci0 + C_ / 2; ++ci) {
    const float* ip = ib + ci * N_;
    const float* wp0 = w0r + ci * 9;
    const float* wp1 = w1r + ci * 9;
#pragma unroll
    for (int ky = 0; ky < 3; ++ky) {
      int iyy = yy + ky - 1;
      if ((unsigned)iyy >= (unsigned)H_) continue;
      const float* rp = ip + iyy * W_;
      float2 mid = *(const float2*)(rp + x0);
      float vL = (x0 > 0) ? rp[x0 - 1] : 0.f;
      float vR = (x0 + 2 < W_) ? rp[x0 + 2] : 0.f;
      float u0 = wp0[ky*3], u1 = wp0[ky*3+1], u2 = wp0[ky*3+2];
      float t0 = wp1[ky*3], t1 = wp1[ky*3+1], t2 = wp1[ky*3+2];
      a00 += vL*u0 + mid.x*u1 + mid.y*u2;
      a01 += mid.x*u0 + mid.y*u1 + vR*u2;
      a10 += vL*t0 + mid.x*t1 + mid.y*t2;
      a11 += mid.x*t0 + mid.y*t1 + vR*t2;
    }
  }
  float* ob = (half ? pB : pA) + (size_t)img * CN_ + (size_t)c0 * N_ + p;
  *(float2*)(ob)      = make_float2(a00, a01);
  *(float2*)(ob + N_) = make_float2(a10, a11);
}

// ------ combine halves + bias + bn + relu (conv1 epilogue) ----------------
__global__ void k_combp(const float* __restrict__ pA, const float* __restrict__ pB,
                        const float* __restrict__ cb,
                        const float* __restrict__ g, const float* __restrict__ b2,
                        const float* __restrict__ m, const float* __restrict__ v,
                        float* __restrict__ tA, float* __restrict__ tB) {
  int t = blockIdx.x * 256 + threadIdx.x;
  int p4 = t * 4;
  int n = p4 % N_;
  int c = (p4 / N_) % C_;
  int img = p4 / (int)CN_;
  size_t off = (size_t)img * CN_ + (size_t)c * N_ + n;
  float4 a = *(const float4*)(pA + off);
  float4 d = *(const float4*)(pB + off);
  float s  = g[c] * rsqrtf(v[c] + EPS_);
  float sh = b2[c] - m[c] * s;
  float bias = cb[c];
  float4 r;
  r.x = fmaxf((a.x + d.x + bias) * s + sh, 0.f);
  r.y = fmaxf((a.y + d.y + bias) * s + sh, 0.f);
  r.z = fmaxf((a.z + d.z + bias) * s + sh, 0.f);
  r.w = fmaxf((a.w + d.w + bias) * s + sh, 0.f);
  float* ob = (img < 2) ? tA + off : tB + off - 2 * CN_;
  *(float4*)ob = r;
}

// ------ combine halves + bias + bn + relu + resid (conv2 epilogue) --------
__global__ void k_comb2(float* __restrict__ pA, const float* __restrict__ pB,
                        const float* __restrict__ cb,
                        const float* __restrict__ g, const float* __restrict__ b2,
                        const float* __restrict__ m, const float* __restrict__ v,
                        const float* __restrict__ resid) {
  int t = blockIdx.x * 256 + threadIdx.x;
  int p4 = t * 4;
  int n = p4 % N_;
  int c = (p4 / N_) % C_;
  int img = p4 / (int)CN_;
  size_t off = (size_t)img * CN_ + (size_t)c * N_ + n;
  float4 a = *(const float4*)(pA + off);
  float4 d = *(const float4*)(pB + off);
  float4 rr = *(const float4*)(resid + off);
  float s  = g[c] * rsqrtf(v[c] + EPS_);
  float sh = b2[c] - m[c] * s;
  float bias = cb[c];
  float4 r;
  r.x = fmaxf((a.x + d.x + bias) * s + sh, 0.f) + rr.x;
  r.y = fmaxf((a.y + d.y + bias) * s + sh, 0.f) + rr.y;
  r.z = fmaxf((a.z + d.z + bias) * s + sh, 0.f) + rr.z;
  r.w = fmaxf((a.w + d.w + bias) * s + sh, 0.f) + rr.w;
  *(float4*)(pA + off) = r;
}

// ------ cat = [xo+yo ; xo*yo] + bn2 -> fin, float4 ------------------------
__global__ void k_catbn(const float* __restrict__ o2,
                        const float* __restrict__ g, const float* __restrict__ b2,
                        const float* __restrict__ m, const float* __restrict__ v,
                        float* __restrict__ cat, float* __restrict__ fin,
                        size_t finStride) {
  int t = blockIdx.x * 256 + threadIdx.x;
  int p4 = t * 4;
  int n  = p4 % N_;
  int c2 = (p4 / N_) % (2 * C_);
  int b  = p4 / (2 * C_ * N_);
  int c  = c2 & 63;
  float4 X = *(const float4*)(o2 + (size_t)b * CN_ + (size_t)c * N_ + n);
  float4 Y = *(const float4*)(o2 + (size_t)(2 + b) * CN_ + (size_t)c * N_ + n);
  float4 val;
  if (c2 < C_) val = make_float4(X.x + Y.x, X.y + Y.y, X.z + Y.z, X.w + Y.w);
  else         val = make_float4(X.x * Y.x, X.y * Y.y, X.z * Y.z, X.w * Y.w);
  size_t co = ((size_t)b * 2 * C_ + c2) * N_ + n;
  *(float4*)(cat + co) = val;
  float s  = g[c2] * rsqrtf(v[c2] + EPS_);
  float sh = b2[c2] - m[c2] * s;
  *(float4*)(fin + (size_t)b * finStride + (size_t)c2 * N_ + n) =
      make_float4(val.x * s + sh, val.y * s + sh, val.z * s + sh, val.w * s + sh);
}

// ------ f-branch 3x3 conv partial (64-cin half), 2 couts + 2 px -----------
// grid (18, C_, 2*B_), block 64. z: b = z&1, half = z>>1.
__global__ __launch_bounds__(64) void k_fconvs(
    const float* __restrict__ in, size_t inStride,
    const float* __restrict__ w,
    float* __restrict__ outA, size_t outStrideA,
    float* __restrict__ outB, size_t outStrideB) {
  int p = blockIdx.x * 128 + threadIdx.x * 2;
  int c0 = blockIdx.y * 2;
  int z = blockIdx.z;
  int b = z & 1, half = z >> 1;
  int yy = p / W_, x0 = p % W_;
  const float* ib = in + (size_t)b * inStride;
  const float* w0r = w + (size_t)c0 * (2 * C_) * 9;
  const float* w1r = w0r + (size_t)(2 * C_) * 9;
  float a00 = 0.f, a01 = 0.f, a10 = 0.f, a11 = 0.f;
  int ci0 = half * C_;
#pragma unroll 4
  for (int ci = ci0; ci < ci0 + C_; ++ci) {
    const float* ip = ib + ci * N_;
    const float* wp0 = w0r + ci * 9;
    const float* wp1 = w1r + ci * 9;
#pragma unroll
    for (int ky = 0; ky < 3; ++ky) {
      int iyy = yy + ky - 1;
      if ((unsigned)iyy >= (unsigned)H_) continue;
      const float* rp = ip + iyy * W_;
      float2 mid = *(const float2*)(rp + x0);
      float vL = (x0 > 0) ? rp[x0 - 1] : 0.f;
      float vR = (x0 + 2 < W_) ? rp[x0 + 2] : 0.f;
      float u0 = wp0[ky*3], u1 = wp0[ky*3+1], u2 = wp0[ky*3+2];
      float t0 = wp1[ky*3], t1 = wp1[ky*3+1], t2 = wp1[ky*3+2];
      a00 += vL*u0 + mid.x*u1 + mid.y*u2;
      a01 += mid.x*u0 + mid.y*u1 + vR*u2;
      a10 += vL*t0 + mid.x*t1 + mid.y*t2;
      a11 += mid.x*t0 + mid.y*t1 + vR*t2;
    }
  }
  float* ob = (half ? outB + (size_t)b * outStrideB
                    : outA + (size_t)b * outStrideA);
  size_t o = (size_t)c0 * N_ + p;
  *(float2*)(ob + o)      = make_float2(a00, a01);
  *(float2*)(ob + o + N_) = make_float2(a10, a11);
}

// ------ combine halves + bn + relu, float4 (in-place into A ok) -----------
__global__ void k_comb(const float* __restrict__ pA, size_t strideA,
                       const float* __restrict__ pB, size_t strideB,
                       const float* __restrict__ g, const float* __restrict__ b2,
                       const float* __restrict__ m, const float* __restrict__ v,
                       float* __restrict__ out, size_t outStride) {
  int t = blockIdx.x * 256 + threadIdx.x;
  int p4 = t * 4;
  int n = p4 % N_;
  int c = (p4 / N_) % (2 * C_);
  int b = p4 / (2 * C_ * N_);
  size_t off = (size_t)c * N_ + n;
  float4 a = *(const float4*)(pA + (size_t)b * strideA + off);
  float4 d = *(const float4*)(pB + (size_t)b * strideB + off);
  float s  = g[c] * rsqrtf(v[c] + EPS_);
  float sh = b2[c] - m[c] * s;
  float4 r;
  r.x = fmaxf((a.x + d.x) * s + sh, 0.f);
  r.y = fmaxf((a.y + d.y) * s + sh, 0.f);
  r.z = fmaxf((a.z + d.z) * s + sh, 0.f);
  r.w = fmaxf((a.w + d.w) * s + sh, 0.f);
  *(float4*)(out + (size_t)b * outStride + off) = r;
}

// -------- final 1x1 conv over fused comb(pA,pB)+bn+relu, + cat add --------
// grid (18, 2C, B), block 64. bn scale/shift precomputed into LDS.
__global__ __launch_bounds__(64) void k_final3(
    const float* __restrict__ pA, size_t strideA,
    const float* __restrict__ pB, size_t strideB,
    const float* __restrict__ g2, const float* __restrict__ b2,
    const float* __restrict__ m2, const float* __restrict__ v2,
    const float* __restrict__ cat,
    const float* __restrict__ w, const float* __restrict__ fb,
    float* __restrict__ out) {
  __shared__ float fsc[2 * C_], fsh[2 * C_];
  for (int j = threadIdx.x; j < 2 * C_; j += 64) {
    float s = g2[j] * rsqrtf(v2[j] + EPS_);
    fsc[j] = s;
    fsh[j] = b2[j] - m2[j] * s;
  }
  __syncthreads();
  int p = blockIdx.x * 128 + threadIdx.x * 2;
  int c = blockIdx.y, b = blockIdx.z;
  const float* frA = pA + (size_t)b * strideA;
  const float* frB = pB + (size_t)b * strideB;
  const float* wr = w + (size_t)c * 2 * C_;
  float a0 = fb[c], a1 = a0;
#pragma unroll 4
  for (int j = 0; j < 2 * C_; ++j) {
    float2 fa = *(const float2*)(frA + (size_t)j * N_ + p);
    float2 fd = *(const float2*)(frB + (size_t)j * N_ + p);
    float s = fsc[j], sh = fsh[j];
    float f0 = fmaxf((fa.x + fd.x) * s + sh, 0.f);
    float f1 = fmaxf((fa.y + fd.y) * s + sh, 0.f);
    float wv = wr[j];
    a0 += wv * f0; a1 += wv * f1;
  }
  size_t o = ((size_t)b * 2 * C_ + c) * N_ + p;
  float2 cv = *(const float2*)(cat + o);
  *(float2*)(out + o) = make_float2(a0 + cv.x, a1 + cv.y);
}

extern "C" void kernel_launch(void* const* d_in, const int* in_sizes, int n_in,
                              void* d_out, int out_size, void* d_ws, size_t ws_size,
                              hipStream_t stream) {
  const float* x       = (const float*)d_in[0];
  const float* y       = (const float*)d_in[1];
  const float* pconv_w = (const float*)d_in[2];
  const float* pconv_b = (const float*)d_in[3];
  const float* bnd_g = (const float*)d_in[4];
  const float* bnd_b = (const float*)d_in[5];
  const float* bnd_m = (const float*)d_in[6];
  const float* bnd_v = (const float*)d_in[7];
  const float* lnx_g = (const float*)d_in[8];
  const float* lnx_b = (const float*)d_in[9];
  const float* lny_g = (const float*)d_in[10];
  const float* lny_b = (const float*)d_in[11];
  const float* lnz_g = (const float*)d_in[12];
  const float* lnz_b = (const float*)d_in[13];
  const float* k_w   = (const float*)d_in[14];
  const float* k_b   = (const float*)d_in[15];
  const float* qv_w  = (const float*)d_in[16];
  const float* qv_b  = (const float*)d_in[17];
  const float* proj_w = (const float*)d_in[18];
  const float* proj_b = (const float*)d_in[19];
  const float* c2w1  = (const float*)d_in[20];
  const float* c2b1  = (const float*)d_in[21];
  const float* c2bn1_g = (const float*)d_in[22];
  const float* c2bn1_b = (const float*)d_in[23];
  const float* c2bn1_m = (const float*)d_in[24];
  const float* c2bn1_v = (const float*)d_in[25];
  const float* c2w2  = (const float*)d_in[26];
  const float* c2b2  = (const float*)d_in[27];
  const float* c2bn2_g = (const float*)d_in[28];
  const float* c2bn2_b = (const float*)d_in[29];
  const float* c2bn2_m = (const float*)d_in[30];
  const float* c2bn2_v = (const float*)d_in[31];
  const float* bn2_g = (const float*)d_in[32];
  const float* bn2_b = (const float*)d_in[33];
  const float* bn2_m = (const float*)d_in[34];
  const float* bn2_v = (const float*)d_in[35];
  const float* f1w   = (const float*)d_in[36];
  const float* fbn1_g = (const float*)d_in[37];
  const float* fbn1_b = (const float*)d_in[38];
  const float* fbn1_m = (const float*)d_in[39];
  const float* fbn1_v = (const float*)d_in[40];
  const float* f2w   = (const float*)d_in[41];
  const float* fbn2_g = (const float*)d_in[42];
  const float* fbn2_b = (const float*)d_in[43];
  const float* fbn2_m = (const float*)d_in[44];
  const float* fbn2_v = (const float*)d_in[45];
  const float* f3w   = (const float*)d_in[46];
  const float* f3b   = (const float*)d_in[47];

  // 8-slot workspace plan (same as R15):
  //   A: k_pre -> xl(1) yl(2) zl(3)
  //   B: qvk -> xq(4) xv(5) yq(6) yv(7); kk(0)
  //   C: attn8 -> att_xo(1) att_yo(2)
  //   D: proj -> xo4(3,4) [img*CN, imgs 0..3]
  //   E1: convs(conv1) raw partials: half0 -> (1,2), half1 -> (5,6)
  //   E2: combp (+bias/bn/relu) -> tmp imgs01 (0), imgs23 (7)
  //   F1: convs(conv2) raw partials from tmp -> (1,2)(5,6)
  //   F2: comb2 (+bias/bn/relu + resid(3,4)) -> o2 in-place (1,2)
  //   G: catbn reads o2(1,2) -> cat(3,4), fin b0->(0), b1->(7) [stride 7S]
  //   H1: fconvs f1: fin(0/7) -> half0 (1,2 stride S), half1 (5,6 stride S)
  //   H2: comb -> (1,2) in-place
  //   H3: fconvs f2: (1,2) -> half0 (5,6), half1 (0/7)
  //   I: final3 reads (5,6)+(0/7), cat(3,4) -> out
  float* ws = (float*)d_ws;
  float* sl0 = ws + 0 * S_;
  float* sl1 = ws + 1 * S_;
  float* sl2 = ws + 2 * S_;
  float* sl3 = ws + 3 * S_;
  float* sl4 = ws + 4 * S_;
  float* sl5 = ws + 5 * S_;
  float* sl7 = ws + 7 * S_;

  // A. fused pconv + bn + ln
  k_pre<<<B_ * N_, 64, 0, stream>>>(x, y, pconv_w, pconv_b,
                                    bnd_g, bnd_b, bnd_m, bnd_v,
                                    lnx_g, lnx_b, lny_g, lny_b, lnz_g, lnz_b,
                                    sl1, sl2, sl3);
  // B. fused qv + kproj
  {
    dim3 g(2304, 1, 3);
    k_qvk<<<g, 256, 0, stream>>>(sl1, sl3, qv_w, qv_b, k_w, k_b, sl4, sl5, sl0);
  }
  // C. attention v8 -> att_xo(1), att_yo(2)
  {
    dim3 g(N_ / 64, B_ * NH_);
    k_attn8<<<g, 1024, 0, stream>>>(sl4, sl5, ws + 6 * S_, ws + 7 * S_, sl0,
                                    sl1, sl2);
  }
  // D. proj batched -> xo4(3,4)
  {
    dim3 g(18, C_, 2 * B_);
    k_proj2<<<g, 64, 0, stream>>>(sl1, x, y, bnd_g, bnd_b, bnd_m, bnd_v,
                                  proj_w, proj_b, sl3);
  }
  // E. conv1: cin-split raw partials + combine epilogue -> tmp(0 / 7)
  {
    dim3 g(18, C_ / 2, 8);
    k_convs<<<g, 64, 0, stream>>>(sl3, sl3 + 2 * CN_, c2w1, sl1, sl5);
    k_combp<<<576, 256, 0, stream>>>(sl1, sl5, c2b1,
        c2bn1_g, c2bn1_b, c2bn1_m, c2bn1_v, sl0, sl7);
  }
  // F. conv2: cin-split raw partials + combine(+resid) -> o2(1,2)
  {
    dim3 g(18, C_ / 2, 8);
    k_convs<<<g, 64, 0, stream>>>(sl0, sl7, c2w2, sl1, sl5);
    k_comb2<<<576, 256, 0, stream>>>(sl1, sl5, c2b2,
        c2bn2_g, c2bn2_b, c2bn2_m, c2bn2_v, sl3);
  }
  // G. cat + bn2 -> cat(3,4), fin(0 / 7)
  k_catbn<<<576, 256, 0, stream>>>(sl1, bn2_g, bn2_b, bn2_m, bn2_v,
                                   sl3, sl0, 7 * S_);
  // H. f-branch convs, ci-split, 2 px/thread
  {
    dim3 g(18, C_, 2 * B_);
    k_fconvs<<<g, 64, 0, stream>>>(sl0, 7 * S_, f1w, sl1, S_, sl5, S_);
    k_comb<<<576, 256, 0, stream>>>(sl1, S_, sl5, S_,
                                    fbn1_g, fbn1_b, fbn1_m, fbn1_v, sl1, S_);
    k_fconvs<<<g, 64, 0, stream>>>(sl1, S_, f2w, sl5, S_, sl0, 7 * S_);
  }
  // I. final 1x1 fused with comb(fbn2) + cat add -> fp32 out
  {
    dim3 g(18, 2 * C_, B_);
    k_final3<<<g, 64, 0, stream>>>(sl5, S_, sl0, 7 * S_,
                                   fbn2_g, fbn2_b, fbn2_m, fbn2_v,
                                   sl3, f3w, f3b, (float*)d_out);
  }
}

// Round 17
// 631.281 us; speedup vs baseline: 1.1670x; 1.0310x over previous
//
#include <hip/hip_runtime.h>
#include <hip/hip_bf16.h>

#define B_   2
#define C_   64
#define H_   48
#define W_   48
#define N_   (H_*W_)     // 2304
#define NH_  8
#define HD_  8
#define EPS_ 1e-5f
#define S2_  0.125f      // scale^2 = 1/hd
#define LOG2E_ 1.44269504f
#define S_   ((size_t)B_ * C_ * N_)   // 294912 floats per workspace slot
#define CN_  ((size_t)C_ * N_)        // 147456 floats per image

__device__ __forceinline__ float wsum64(float v) {
#pragma unroll
  for (int o = 32; o > 0; o >>= 1) v += __shfl_xor(v, o, 64);
  return v;
}

__device__ __forceinline__ float ln_val(float t, float g, float b) {
  float mu  = wsum64(t) * (1.0f / 64.0f);
  float d   = t - mu;
  float var = wsum64(d * d) * (1.0f / 64.0f);
  return d * rsqrtf(var + EPS_) * g + b;
}

// ---- fused 1x1 pconv + BN + 3x LayerNorm; block = one (b,n) row ----------
__global__ __launch_bounds__(64) void k_pre(
    const float* __restrict__ x, const float* __restrict__ y,
    const float* __restrict__ pw, const float* __restrict__ pb,
    const float* g, const float* bb, const float* m, const float* v,
    const float* lnxg, const float* lnxb,
    const float* lnyg, const float* lnyb,
    const float* lnzg, const float* lnzb,
    float* __restrict__ xl, float* __restrict__ yl, float* __restrict__ zl) {
  __shared__ float xs[64], ys[64];
  int row = blockIdx.x;            // b*N + n
  int c = threadIdx.x;
  int b = row / N_, n = row % N_;
  float xv = x[(size_t)(b * C_ + c) * N_ + n];
  float yv = y[(size_t)(b * C_ + c) * N_ + n];
  xs[c] = xv; ys[c] = yv;
  __syncthreads();
  const float4* wr  = (const float4*)(pw + (size_t)c * 2 * C_);
  const float4* xs4 = (const float4*)xs;
  const float4* ys4 = (const float4*)ys;
  float acc = pb[c];
#pragma unroll
  for (int t = 0; t < 16; ++t) {
    float4 a = xs4[t], wv = wr[t];
    acc += a.x * wv.x + a.y * wv.y + a.z * wv.z + a.w * wv.w;
  }
#pragma unroll
  for (int t = 0; t < 16; ++t) {
    float4 a = ys4[t], wv = wr[16 + t];
    acc += a.x * wv.x + a.y * wv.y + a.z * wv.z + a.w * wv.w;
  }
  float s  = g[c] * rsqrtf(v[c] + EPS_);
  float sh = bb[c] - m[c] * s;
  float tx = xv * s + sh;
  xl[(size_t)row * C_ + c] = ln_val(tx, lnxg[c], lnxb[c]);
  float ty = yv * s + sh;
  yl[(size_t)row * C_ + c] = ln_val(ty, lnyg[c], lnyb[c]);
  float tz = acc * s + sh;
  zl[(size_t)row * C_ + c] = ln_val(tz, lnzg[c], lnzb[c]);
}

// ------------- fused qv (both branches) + k projection --------------------
__global__ void k_qvk(const float* __restrict__ lnb, const float* __restrict__ zl,
                      const float* __restrict__ qvw, const float* __restrict__ qvb,
                      const float* __restrict__ kw, const float* __restrict__ kb,
                      float* __restrict__ qb, float* __restrict__ vb,
                      float* __restrict__ kk) {
  int z = blockIdx.z;
  if (z < 2) {
    int idx = blockIdx.x * 256 + threadIdx.x;   // B*N*128
    int j = idx & 127;
    int row = idx >> 7;
    int b = row / N_, n = row % N_;
    const float4* ir = (const float4*)(lnb + z * S_ + (size_t)row * C_);
    const float4* wr = (const float4*)(qvw + (size_t)j * C_);
    float acc = qvb[j];
#pragma unroll
    for (int t = 0; t < 16; ++t) {
      float4 a = ir[t], wv = wr[t];
      acc += a.x * wv.x + a.y * wv.y + a.z * wv.z + a.w * wv.w;
    }
    int jj = j & 63;
    int h = jj >> 3, d = jj & 7;
    float* dst = ((j < C_) ? qb : vb) + z * 2 * S_;
    dst[((size_t)(b * NH_ + h) * N_ + n) * HD_ + d] = acc;
  } else {
    if (blockIdx.x >= 1152) return;
    int idx = blockIdx.x * 256 + threadIdx.x;   // B*N*64
    int j = idx & 63;
    int row = idx >> 6;
    int b = row / N_, n = row % N_;
    const float4* ir = (const float4*)(zl + (size_t)row * C_);
    const float4* wr = (const float4*)(kw + (size_t)j * C_);
    float acc = kb[j];
#pragma unroll
    for (int t = 0; t < 16; ++t) {
      float4 a = ir[t], wv = wr[t];
      acc += a.x * wv.x + a.y * wv.y + a.z * wv.z + a.w * wv.w;
    }
    int h = j >> 3, d = j & 7;
    kk[((size_t)(b * NH_ + h) * N_ + n) * HD_ + d] = acc;
  }
}

// ---------------- attention v7: 16 waves, no-max, 2-key ILP ---------------
#define AW 16
__global__ __launch_bounds__(1024, 8) void k_attn7(
    const float* __restrict__ xq, const float* __restrict__ xv,
    const float* __restrict__ yq, const float* __restrict__ yv,
    const float* __restrict__ kk,
    float* __restrict__ outx, float* __restrict__ outy) {
  __shared__ float pl[AW][64];
  __shared__ float pbuf[AW][8][64];
  int bh  = blockIdx.y;
  int qt  = blockIdx.x;
  int tid = threadIdx.x;
  int lane = tid & 63;
  int wave = __builtin_amdgcn_readfirstlane(tid >> 6);
  int q = qt * 64 + lane;
  size_t base = (size_t)bh * N_ * HD_;

  float4 qx0 = ((const float4*)(xq + base + (size_t)q * HD_))[0];
  float4 qx1 = ((const float4*)(xq + base + (size_t)q * HD_))[1];
  float4 qy0 = ((const float4*)(yq + base + (size_t)q * HD_))[0];
  float4 qy1 = ((const float4*)(yq + base + (size_t)q * HD_))[1];
  const float fs = S2_ * LOG2E_;
  qx0.x *= fs; qx0.y *= fs; qx0.z *= fs; qx0.w *= fs;
  qx1.x *= fs; qx1.y *= fs; qx1.z *= fs; qx1.w *= fs;

  float l = 0.f;
  float ax[8] = {0,0,0,0,0,0,0,0};
  float ay[8] = {0,0,0,0,0,0,0,0};

  const float4* kp = (const float4*)(kk + base);
  const float4* xp = (const float4*)(xv + base);
  const float4* yp = (const float4*)(yv + base);
  int k0 = wave * (N_ / AW);
  for (int mi = k0; mi < k0 + N_ / AW; mi += 2) {
    float4 kaA  = kp[2 * mi],     kbA = kp[2 * mi + 1];
    float4 kaB  = kp[2 * mi + 2], kbB = kp[2 * mi + 3];
    float4 xaA = xp[2 * mi],     xbA = xp[2 * mi + 1];
    float4 xaB = xp[2 * mi + 2], xbB = xp[2 * mi + 3];
    float4 yaA = yp[2 * mi],     ybA = yp[2 * mi + 1];
    float4 yaB = yp[2 * mi + 2], ybB = yp[2 * mi + 3];
    float s1A = qx0.x*kaA.x + qx0.y*kaA.y + qx0.z*kaA.z + qx0.w*kaA.w
              + qx1.x*kbA.x + qx1.y*kbA.y + qx1.z*kbA.z + qx1.w*kbA.w;
    float s2A = qy0.x*kaA.x + qy0.y*kaA.y + qy0.z*kaA.z + qy0.w*kaA.w
              + qy1.x*kbA.x + qy1.y*kbA.y + qy1.z*kbA.z + qy1.w*kbA.w;
    float s1B = qx0.x*kaB.x + qx0.y*kaB.y + qx0.z*kaB.z + qx0.w*kaB.w
              + qx1.x*kbB.x + qx1.y*kbB.y + qx1.z*kbB.z + qx1.w*kbB.w;
    float s2B = qy0.x*kaB.x + qy0.y*kaB.y + qy0.z*kaB.z + qy0.w*kaB.w
              + qy1.x*kbB.x + qy1.y*kbB.y + qy1.z*kbB.z + qy1.w*kbB.w;
    float pA = exp2f(s1A * s2A);
    float pB = exp2f(s1B * s2B);
    l += pA + pB;
    ax[0] += pA*xaA.x + pB*xaB.x;  ax[1] += pA*xaA.y + pB*xaB.y;
    ax[2] += pA*xaA.z + pB*xaB.z;  ax[3] += pA*xaA.w + pB*xaB.w;
    ax[4] += pA*xbA.x + pB*xbB.x;  ax[5] += pA*xbA.y + pB*xbB.y;
    ax[6] += pA*xbA.z + pB*xbB.z;  ax[7] += pA*xbA.w + pB*xbB.w;
    ay[0] += pA*yaA.x + pB*yaB.x;  ay[1] += pA*yaA.y + pB*yaB.y;
    ay[2] += pA*yaA.z + pB*yaB.z;  ay[3] += pA*yaA.w + pB*yaB.w;
    ay[4] += pA*ybA.x + pB*ybB.x;  ay[5] += pA*ybA.y + pB*ybB.y;
    ay[6] += pA*ybA.z + pB*ybB.z;  ay[7] += pA*ybA.w + pB*ybB.w;
  }
  pl[wave][lane] = l;
#pragma unroll
  for (int d = 0; d < 8; ++d) pbuf[wave][d][lane] = ax[d];
  __syncthreads();
  float Linv = 0.f;
  int b = bh / NH_, h = bh % NH_;
  if (tid < 64) {
    float L = 0.f;
#pragma unroll
    for (int w = 0; w < AW; ++w) L += pl[w][lane];
    Linv = 1.f / L;
    float A[8] = {0,0,0,0,0,0,0,0};
#pragma unroll
    for (int w = 0; w < AW; ++w)
#pragma unroll
      for (int d = 0; d < 8; ++d) A[d] += pbuf[w][d][lane];
    float* o = outx + ((size_t)(b * N_ + q)) * C_ + h * HD_;
#pragma unroll
    for (int d = 0; d < 8; ++d) o[d] = A[d] * Linv;
  }
  __syncthreads();
#pragma unroll
  for (int d = 0; d < 8; ++d) pbuf[wave][d][lane] = ay[d];
  __syncthreads();
  if (tid < 64) {
    float A[8] = {0,0,0,0,0,0,0,0};
#pragma unroll
    for (int w = 0; w < AW; ++w)
#pragma unroll
      for (int d = 0; d < 8; ++d) A[d] += pbuf[w][d][lane];
    float* o = outy + ((size_t)(b * N_ + q)) * C_ + h * HD_;
#pragma unroll
    for (int d = 0; d < 8; ++d) o[d] = A[d] * Linv;
  }
}

// -------- proj + recomputed-BN residual, 2 px/thread ----------------------
// grid (18, C_, 2*B_), block 64. out layout z*CN, z = branch*B_ + b.
__global__ __launch_bounds__(64) void k_proj2(
    const float* __restrict__ attbase,
    const float* __restrict__ x, const float* __restrict__ y,
    const float* bg, const float* bb2, const float* bm, const float* bv,
    const float* __restrict__ pw, const float* __restrict__ pbias,
    float* __restrict__ outbase) {
  int p = blockIdx.x * 128 + threadIdx.x * 2;
  int c = blockIdx.y;
  int z = blockIdx.z;
  int branch = z >> 1, b = z & 1;
  const float* att = attbase + branch * S_ + (size_t)b * N_ * C_;
  const float4* wr = (const float4*)(pw + (size_t)c * C_);
  float bias = pbias[c];
  float acc[2];
#pragma unroll
  for (int i = 0; i < 2; ++i) {
    const float4* ar = (const float4*)(att + (size_t)(p + i) * C_);
    float a = bias;
#pragma unroll
    for (int t = 0; t < 16; ++t) {
      float4 av = ar[t], wv = wr[t];
      a += av.x * wv.x + av.y * wv.y + av.z * wv.z + av.w * wv.w;
    }
    acc[i] = a;
  }
  float s  = bg[c] * rsqrtf(bv[c] + EPS_);
  float sh = bb2[c] - bm[c] * s;
  const float* xin = branch ? y : x;
  float2 r = *(const float2*)(xin + ((size_t)b * C_ + c) * N_ + p);
  size_t o = (size_t)z * CN_ + (size_t)c * N_ + p;
  *(float2*)(outbase + o) = make_float2(acc[0] + r.x * s + sh,
                                        acc[1] + r.y * s + sh);
}

// ------ 64-cin conv RAW partial: cin half, 2 couts + 4 px -----------------
// grid (9, C_/2, 8), block 64. z: img = z&3 (layout img*CN), half = z>>2.
__global__ __launch_bounds__(64) void k_convs(
    const float* __restrict__ inA, const float* __restrict__ inB,
    const float* __restrict__ w,
    float* __restrict__ pA, float* __restrict__ pB) {
  int p = blockIdx.x * 256 + threadIdx.x * 4;
  int c0 = blockIdx.y * 2;
  int z = blockIdx.z;
  int img = z & 3, half = z >> 2;
  int yy = p / W_, x0 = p % W_;      // x0 in {0,4,...,44}; row-contained
  const float* ib = (img < 2) ? inA + (size_t)img * CN_
                              : inB + (size_t)(img - 2) * CN_;
  const float* w0r = w + (size_t)c0 * C_ * 9;
  const float* w1r = w0r + (size_t)C_ * 9;
  float a0 = 0.f, a1 = 0.f, a2 = 0.f, a3 = 0.f;
  float b0 = 0.f, b1 = 0.f, b2 = 0.f, b3 = 0.f;
  int ci0 = half * (C_ / 2);
#pragma unroll 2
  for (int ci = ci0; ci < ci0 + C_ / 2; ++ci) {
    const float* ip = ib + ci * N_;
    const float* wp0 = w0r + ci * 9;
    const float* wp1 = w1r + ci * 9;
#pragma unroll
    for (int ky = 0; ky < 3; ++ky) {
      int iyy = yy + ky - 1;
      if ((unsigned)iyy >= (unsigned)H_) continue;
      const float* rp = ip + iyy * W_;
      float4 mid = *(const float4*)(rp + x0);
      float vL = (x0 > 0) ? rp[x0 - 1] : 0.f;
      float vR = (x0 + 4 < W_) ? rp[x0 + 4] : 0.f;
      float u0 = wp0[ky*3], u1 = wp0[ky*3+1], u2 = wp0[ky*3+2];
      float t0 = wp1[ky*3], t1 = wp1[ky*3+1], t2 = wp1[ky*3+2];
      a0 += vL    * u0 + mid.x * u1 + mid.y * u2;
      a1 += mid.x * u0 + mid.y * u1 + mid.z * u2;
      a2 += mid.y * u0 + mid.z * u1 + mid.w * u2;
      a3 += mid.z * u0 + mid.w * u1 + vR    * u2;
      b0 += vL    * t0 + mid.x * t1 + mid.y * t2;
      b1 += mid.x * t0 + mid.y * t1 + mid.z * t2;
      b2 += mid.y * t0 + mid.z * t1 + mid.w * t2;
      b3 += mid.z * t0 + mid.w * t1 + vR    * t2;
    }
  }
  float* ob = (half ? pB : pA) + (size_t)img * CN_ + (size_t)c0 * N_ + p;
  *(float4*)(ob)      = make_float4(a0, a1, a2, a3);
  *(float4*)(ob + N_) = make_float4(b0, b1, b2, b3);
}

// ------ combine halves + bias + bn + relu (conv1 epilogue) ----------------
__global__ void k_combp(const float* __restrict__ pA, const float* __restrict__ pB,
                        const float* __restrict__ cb,
                        const float* __restrict__ g, const float* __restrict__ b2,
                        const float* __restrict__ m, const float* __restrict__ v,
                        float* __restrict__ tA, float* __restrict__ tB) {
  int t = blockIdx.x * 256 + threadIdx.x;
  int p4 = t * 4;
  int n = p4 % N_;
  int c = (p4 / N_) % C_;
  int img = p4 / (int)CN_;
  size_t off = (size_t)img * CN_ + (size_t)c * N_ + n;
  float4 a = *(const float4*)(pA + off);
  float4 d = *(const float4*)(pB + off);
  float s  = g[c] * rsqrtf(v[c] + EPS_);
  float sh = b2[c] - m[c] * s;
  float bias = cb[c];
  float4 r;
  r.x = fmaxf((a.x + d.x + bias) * s + sh, 0.f);
  r.y = fmaxf((a.y + d.y + bias) * s + sh, 0.f);
  r.z = fmaxf((a.z + d.z + bias) * s + sh, 0.f);
  r.w = fmaxf((a.w + d.w + bias) * s + sh, 0.f);
  float* ob = (img < 2) ? tA + off : tB + off - 2 * CN_;
  *(float4*)ob = r;
}

// ------ combine halves + bias + bn + relu + resid (conv2 epilogue) --------
__global__ void k_comb2(float* __restrict__ pA, const float* __restrict__ pB,
                        const float* __restrict__ cb,
                        const float* __restrict__ g, const float* __restrict__ b2,
                        const float* __restrict__ m, const float* __restrict__ v,
                        const float* __restrict__ resid) {
  int t = blockIdx.x * 256 + threadIdx.x;
  int p4 = t * 4;
  int n = p4 % N_;
  int c = (p4 / N_) % C_;
  int img = p4 / (int)CN_;
  size_t off = (size_t)img * CN_ + (size_t)c * N_ + n;
  float4 a = *(const float4*)(pA + off);
  float4 d = *(const float4*)(pB + off);
  float4 rr = *(const float4*)(resid + off);
  float s  = g[c] * rsqrtf(v[c] + EPS_);
  float sh = b2[c] - m[c] * s;
  float bias = cb[c];
  float4 r;
  r.x = fmaxf((a.x + d.x + bias) * s + sh, 0.f) + rr.x;
  r.y = fmaxf((a.y + d.y + bias) * s + sh, 0.f) + rr.y;
  r.z = fmaxf((a.z + d.z + bias) * s + sh, 0.f) + rr.z;
  r.w = fmaxf((a.w + d.w + bias) * s + sh, 0.f) + rr.w;
  *(float4*)(pA + off) = r;
}

// ------ cat = [xo+yo ; xo*yo] + bn2 -> fin, float4 ------------------------
__global__ void k_catbn(const float* __restrict__ o2,
                        const float* __restrict__ g, const float* __restrict__ b2,
                        const float* __restrict__ m, const float* __restrict__ v,
                        float* __restrict__ cat, float* __restrict__ fin,
                        size_t finStride) {
  int t = blockIdx.x * 256 + threadIdx.x;
  int p4 = t * 4;
  int n  = p4 % N_;
  int c2 = (p4 / N_) % (2 * C_);
  int b  = p4 / (2 * C_ * N_);
  int c  = c2 & 63;
  float4 X = *(const float4*)(o2 + (size_t)b * CN_ + (size_t)c * N_ + n);
  float4 Y = *(const float4*)(o2 + (size_t)(2 + b) * CN_ + (size_t)c * N_ + n);
  float4 val;
  if (c2 < C_) val = make_float4(X.x + Y.x, X.y + Y.y, X.z + Y.z, X.w + Y.w);
  else         val = make_float4(X.x * Y.x, X.y * Y.y, X.z * Y.z, X.w * Y.w);
  size_t co = ((size_t)b * 2 * C_ + c2) * N_ + n;
  *(float4*)(cat + co) = val;
  float s  = g[c2] * rsqrtf(v[c2] + EPS_);
  float sh = b2[c2] - m[c2] * s;
  *(float4*)(fin + (size_t)b * finStride + (size_t)c2 * N_ + n) =
      make_float4(val.x * s + sh, val.y * s + sh, val.z * s + sh, val.w * s + sh);
}

// ------ f-branch 3x3 conv partial (64-cin half), 2 couts + 4 px -----------
// grid (9, C_, 2*B_), block 64. z: b = z&1, half = z>>1.
__global__ __launch_bounds__(64) void k_fconvs(
    const float* __restrict__ in, size_t inStride,
    const float* __restrict__ w,
    float* __restrict__ outA, size_t outStrideA,
    float* __restrict__ outB, size_t outStrideB) {
  int p = blockIdx.x * 256 + threadIdx.x * 4;
  int c0 = blockIdx.y * 2;
  int z = blockIdx.z;
  int b = z & 1, half = z >> 1;
  int yy = p / W_, x0 = p % W_;
  const float* ib = in + (size_t)b * inStride;
  const float* w0r = w + (size_t)c0 * (2 * C_) * 9;
  const float* w1r = w0r + (size_t)(2 * C_) * 9;
  float a0 = 0.f, a1 = 0.f, a2 = 0.f, a3 = 0.f;
  float b0 = 0.f, b1 = 0.f, b2 = 0.f, b3 = 0.f;
  int ci0 = half * C_;
#pragma unroll 2
  for (int ci = ci0; ci < ci0 + C_; ++ci) {
    const float* ip = ib + ci * N_;
    const float* wp0 = w0r + ci * 9;
    const float* wp1 = w1r + ci * 9;
#pragma unroll
    for (int ky = 0; ky < 3; ++ky) {
      int iyy = yy + ky - 1;
      if ((unsigned)iyy >= (unsigned)H_) continue;
      const float* rp = ip + iyy * W_;
      float4 mid = *(const float4*)(rp + x0);
      float vL = (x0 > 0) ? rp[x0 - 1] : 0.f;
      float vR = (x0 + 4 < W_) ? rp[x0 + 4] : 0.f;
      float u0 = wp0[ky*3], u1 = wp0[ky*3+1], u2 = wp0[ky*3+2];
      float t0 = wp1[ky*3], t1 = wp1[ky*3+1], t2 = wp1[ky*3+2];
      a0 += vL    * u0 + mid.x * u1 + mid.y * u2;
      a1 += mid.x * u0 + mid.y * u1 + mid.z * u2;
      a2 += mid.y * u0 + mid.z * u1 + mid.w * u2;
      a3 += mid.z * u0 + mid.w * u1 + vR    * u2;
      b0 += vL    * t0 + mid.x * t1 + mid.y * t2;
      b1 += mid.x * t0 + mid.y * t1 + mid.z * t2;
      b2 += mid.y * t0 + mid.z * t1 + mid.w * t2;
      b3 += mid.z * t0 + mid.w * t1 + vR    * t2;
    }
  }
  float* ob = (half ? outB + (size_t)b * outStrideB
                    : outA + (size_t)b * outStrideA);
  size_t o = (size_t)c0 * N_ + p;
  *(float4*)(ob + o)      = make_float4(a0, a1, a2, a3);
  *(float4*)(ob + o + N_) = make_float4(b0, b1, b2, b3);
}

// ------ combine halves + bn + relu, float4 (in-place into A ok) -----------
__global__ void k_comb(const float* __restrict__ pA, size_t strideA,
                       const float* __restrict__ pB, size_t strideB,
                       const float* __restrict__ g, const float* __restrict__ b2,
                       const float* __restrict__ m, const float* __restrict__ v,
                       float* __restrict__ out, size_t outStride) {
  int t = blockIdx.x * 256 + threadIdx.x;
  int p4 = t * 4;
  int n = p4 % N_;
  int c = (p4 / N_) % (2 * C_);
  int b = p4 / (2 * C_ * N_);
  size_t off = (size_t)c * N_ + n;
  float4 a = *(const float4*)(pA + (size_t)b * strideA + off);
  float4 d = *(const float4*)(pB + (size_t)b * strideB + off);
  float s  = g[c] * rsqrtf(v[c] + EPS_);
  float sh = b2[c] - m[c] * s;
  float4 r;
  r.x = fmaxf((a.x + d.x) * s + sh, 0.f);
  r.y = fmaxf((a.y + d.y) * s + sh, 0.f);
  r.z = fmaxf((a.z + d.z) * s + sh, 0.f);
  r.w = fmaxf((a.w + d.w) * s + sh, 0.f);
  *(float4*)(out + (size_t)b * outStride + off) = r;
}

// -------- final 1x1 conv over fused comb(pA,pB)+bn+relu, + cat add --------
// grid (18, 2C, B), block 64. bn scale/shift precomputed into LDS.
__global__ __launch_bounds__(64) void k_final3(
    const float* __restrict__ pA, size_t strideA,
    const float* __restrict__ pB, size_t strideB,
    const float* __restrict__ g2, const float* __restrict__ b2,
    const float* __restrict__ m2, const float* __restrict__ v2,
    const float* __restrict__ cat,
    const float* __restrict__ w, const float* __restrict__ fb,
    float* __restrict__ out) {
  __shared__ float fsc[2 * C_], fsh[2 * C_];
  for (int j = threadIdx.x; j < 2 * C_; j += 64) {
    float s = g2[j] * rsqrtf(v2[j] + EPS_);
    fsc[j] = s;
    fsh[j] = b2[j] - m2[j] * s;
  }
  __syncthreads();
  int p = blockIdx.x * 128 + threadIdx.x * 2;
  int c = blockIdx.y, b = blockIdx.z;
  const float* frA = pA + (size_t)b * strideA;
  const float* frB = pB + (size_t)b * strideB;
  const float* wr = w + (size_t)c * 2 * C_;
  float a0 = fb[c], a1 = a0;
#pragma unroll 4
  for (int j = 0; j < 2 * C_; ++j) {
    float2 fa = *(const float2*)(frA + (size_t)j * N_ + p);
    float2 fd = *(const float2*)(frB + (size_t)j * N_ + p);
    float s = fsc[j], sh = fsh[j];
    float f0 = fmaxf((fa.x + fd.x) * s + sh, 0.f);
    float f1 = fmaxf((fa.y + fd.y) * s + sh, 0.f);
    float wv = wr[j];
    a0 += wv * f0; a1 += wv * f1;
  }
  size_t o = ((size_t)b * 2 * C_ + c) * N_ + p;
  float2 cv = *(const float2*)(cat + o);
  *(float2*)(out + o) = make_float2(a0 + cv.x, a1 + cv.y);
}

extern "C" void kernel_launch(void* const* d_in, const int* in_sizes, int n_in,
                              void* d_out, int out_size, void* d_ws, size_t ws_size,
                              hipStream_t stream) {
  const float* x       = (const float*)d_in[0];
  const float* y       = (const float*)d_in[1];
  const float* pconv_w = (const float*)d_in[2];
  const float* pconv_b = (const float*)d_in[3];
  const float* bnd_g = (const float*)d_in[4];
  const float* bnd_b = (const float*)d_in[5];
  const float* bnd_m = (const float*)d_in[6];
  const float* bnd_v = (const float*)d_in[7];
  const float* lnx_g = (const float*)d_in[8];
  const float* lnx_b = (const float*)d_in[9];
  const float* lny_g = (const float*)d_in[10];
  const float* lny_b = (const float*)d_in[11];
  const float* lnz_g = (const float*)d_in[12];
  const float* lnz_b = (const float*)d_in[13];
  const float* k_w   = (const float*)d_in[14];
  const float* k_b   = (const float*)d_in[15];
  const float* qv_w  = (const float*)d_in[16];
  const float* qv_b  = (const float*)d_in[17];
  const float* proj_w = (const float*)d_in[18];
  const float* proj_b = (const float*)d_in[19];
  const float* c2w1  = (const float*)d_in[20];
  const float* c2b1  = (const float*)d_in[21];
  const float* c2bn1_g = (const float*)d_in[22];
  const float* c2bn1_b = (const float*)d_in[23];
  const float* c2bn1_m = (const float*)d_in[24];
  const float* c2bn1_v = (const float*)d_in[25];
  const float* c2w2  = (const float*)d_in[26];
  const float* c2b2  = (const float*)d_in[27];
  const float* c2bn2_g = (const float*)d_in[28];
  const float* c2bn2_b = (const float*)d_in[29];
  const float* c2bn2_m = (const float*)d_in[30];
  const float* c2bn2_v = (const float*)d_in[31];
  const float* bn2_g = (const float*)d_in[32];
  const float* bn2_b = (const float*)d_in[33];
  const float* bn2_m = (const float*)d_in[34];
  const float* bn2_v = (const float*)d_in[35];
  const float* f1w   = (const float*)d_in[36];
  const float* fbn1_g = (const float*)d_in[37];
  const float* fbn1_b = (const float*)d_in[38];
  const float* fbn1_m = (const float*)d_in[39];
  const float* fbn1_v = (const float*)d_in[40];
  const float* f2w   = (const float*)d_in[41];
  const float* fbn2_g = (const float*)d_in[42];
  const float* fbn2_b = (const float*)d_in[43];
  const float* fbn2_m = (const float*)d_in[44];
  const float* fbn2_v = (const float*)d_in[45];
  const float* f3w   = (const float*)d_in[46];
  const float* f3b   = (const float*)d_in[47];

  // 8-slot workspace plan (same as R15/R16):
  //   A: k_pre -> xl(1) yl(2) zl(3)
  //   B: qvk -> xq(4) xv(5) yq(6) yv(7); kk(0)
  //   C: attn7 -> att_xo(1) att_yo(2)
  //   D: proj -> xo4(3,4) [img*CN, imgs 0..3]
  //   E1: convs(conv1) raw partials: half0 -> (1,2), half1 -> (5,6)
  //   E2: combp (+bias/bn/relu) -> tmp imgs01 (0), imgs23 (7)
  //   F1: convs(conv2) raw partials from tmp -> (1,2)(5,6)
  //   F2: comb2 (+bias/bn/relu + resid(3,4)) -> o2 in-place (1,2)
  //   G: catbn reads o2(1,2) -> cat(3,4), fin b0->(0), b1->(7) [stride 7S]
  //   H1: fconvs f1: fin(0/7) -> half0 (1,2 stride S), half1 (5,6 stride S)
  //   H2: comb -> (1,2) in-place
  //   H3: fconvs f2: (1,2) -> half0 (5,6), half1 (0/7)
  //   I: final3 reads (5,6)+(0/7), cat(3,4) -> out
  float* ws = (float*)d_ws;
  float* sl0 = ws + 0 * S_;
  float* sl1 = ws + 1 * S_;
  float* sl2 = ws + 2 * S_;
  float* sl3 = ws + 3 * S_;
  float* sl4 = ws + 4 * S_;
  float* sl5 = ws + 5 * S_;
  float* sl7 = ws + 7 * S_;

  // A. fused pconv + bn + ln
  k_pre<<<B_ * N_, 64, 0, stream>>>(x, y, pconv_w, pconv_b,
                                    bnd_g, bnd_b, bnd_m, bnd_v,
                                    lnx_g, lnx_b, lny_g, lny_b, lnz_g, lnz_b,
                                    sl1, sl2, sl3);
  // B. fused qv + kproj
  {
    dim3 g(2304, 1, 3);
    k_qvk<<<g, 256, 0, stream>>>(sl1, sl3, qv_w, qv_b, k_w, k_b, sl4, sl5, sl0);
  }
  // C. attention v7 -> att_xo(1), att_yo(2)
  {
    dim3 g(N_ / 64, B_ * NH_);
    k_attn7<<<g, 1024, 0, stream>>>(sl4, sl5, ws + 6 * S_, ws + 7 * S_, sl0,
                                    sl1, sl2);
  }
  // D. proj batched -> xo4(3,4)
  {
    dim3 g(18, C_, 2 * B_);
    k_proj2<<<g, 64, 0, stream>>>(sl1, x, y, bnd_g, bnd_b, bnd_m, bnd_v,
                                  proj_w, proj_b, sl3);
  }
  // E. conv1: cin-split raw partials (4 px) + combine epilogue -> tmp(0 / 7)
  {
    dim3 g(9, C_ / 2, 8);
    k_convs<<<g, 64, 0, stream>>>(sl3, sl3 + 2 * CN_, c2w1, sl1, sl5);
    k_combp<<<576, 256, 0, stream>>>(sl1, sl5, c2b1,
        c2bn1_g, c2bn1_b, c2bn1_m, c2bn1_v, sl0, sl7);
  }
  // F. conv2: cin-split raw partials (4 px) + combine(+resid) -> o2(1,2)
  {
    dim3 g(9, C_ / 2, 8);
    k_convs<<<g, 64, 0, stream>>>(sl0, sl7, c2w2, sl1, sl5);
    k_comb2<<<576, 256, 0, stream>>>(sl1, sl5, c2b2,
        c2bn2_g, c2bn2_b, c2bn2_m, c2bn2_v, sl3);
  }
  // G. cat + bn2 -> cat(3,4), fin(0 / 7)
  k_catbn<<<576, 256, 0, stream>>>(sl1, bn2_g, bn2_b, bn2_m, bn2_v,
                                   sl3, sl0, 7 * S_);
  // H. f-branch convs, ci-split, 4 px/thread
  {
    dim3 g(9, C_, 2 * B_);
    k_fconvs<<<g, 64, 0, stream>>>(sl0, 7 * S_, f1w, sl1, S_, sl5, S_);
    k_comb<<<576, 256, 0, stream>>>(sl1, S_, sl5, S_,
                                    fbn1_g, fbn1_b, fbn1_m, fbn1_v, sl1, S_);
    k_fconvs<<<g, 64, 0, stream>>>(sl1, S_, f2w, sl5, S_, sl0, 7 * S_);
  }
  // I. final 1x1 fused with comb(fbn2) + cat add -> fp32 out
  {
    dim3 g(18, 2 * C_, B_);
    k_final3<<<g, 64, 0, stream>>>(sl5, S_, sl0, 7 * S_,
                                   fbn2_g, fbn2_b, fbn2_m, fbn2_v,
                                   sl3, f3w, f3b, (float*)d_out);
  }
}

// Round 18
// 605.597 us; speedup vs baseline: 1.2165x; 1.0424x over previous
//
#include <hip/hip_runtime.h>
#include <hip/hip_bf16.h>

#define B_   2
#define C_   64
#define H_   48
#define W_   48
#define N_   (H_*W_)     // 2304
#define NH_  8
#define HD_  8
#define EPS_ 1e-5f
#define S2_  0.125f      // scale^2 = 1/hd
#define LOG2E_ 1.44269504f
#define S_   ((size_t)B_ * C_ * N_)   // 294912 floats per workspace slot
#define CN_  ((size_t)C_ * N_)        // 147456 floats per image

__device__ __forceinline__ float wsum64(float v) {
#pragma unroll
  for (int o = 32; o > 0; o >>= 1) v += __shfl_xor(v, o, 64);
  return v;
}

__device__ __forceinline__ float ln_val(float t, float g, float b) {
  float mu  = wsum64(t) * (1.0f / 64.0f);
  float d   = t - mu;
  float var = wsum64(d * d) * (1.0f / 64.0f);
  return d * rsqrtf(var + EPS_) * g + b;
}

// ---- fused 1x1 pconv + BN + 3x LayerNorm; block = one (b,n) row ----------
__global__ __launch_bounds__(64) void k_pre(
    const float* __restrict__ x, const float* __restrict__ y,
    const float* __restrict__ pw, const float* __restrict__ pb,
    const float* g, const float* bb, const float* m, const float* v,
    const float* lnxg, const float* lnxb,
    const float* lnyg, const float* lnyb,
    const float* lnzg, const float* lnzb,
    float* __restrict__ xl, float* __restrict__ yl, float* __restrict__ zl) {
  __shared__ float xs[64], ys[64];
  int row = blockIdx.x;            // b*N + n
  int c = threadIdx.x;
  int b = row / N_, n = row % N_;
  float xv = x[(size_t)(b * C_ + c) * N_ + n];
  float yv = y[(size_t)(b * C_ + c) * N_ + n];
  xs[c] = xv; ys[c] = yv;
  __syncthreads();
  const float4* wr  = (const float4*)(pw + (size_t)c * 2 * C_);
  const float4* xs4 = (const float4*)xs;
  const float4* ys4 = (const float4*)ys;
  float acc = pb[c];
#pragma unroll
  for (int t = 0; t < 16; ++t) {
    float4 a = xs4[t], wv = wr[t];
    acc += a.x * wv.x + a.y * wv.y + a.z * wv.z + a.w * wv.w;
  }
#pragma unroll
  for (int t = 0; t < 16; ++t) {
    float4 a = ys4[t], wv = wr[16 + t];
    acc += a.x * wv.x + a.y * wv.y + a.z * wv.z + a.w * wv.w;
  }
  float s  = g[c] * rsqrtf(v[c] + EPS_);
  float sh = bb[c] - m[c] * s;
  float tx = xv * s + sh;
  xl[(size_t)row * C_ + c] = ln_val(tx, lnxg[c], lnxb[c]);
  float ty = yv * s + sh;
  yl[(size_t)row * C_ + c] = ln_val(ty, lnyg[c], lnyb[c]);
  float tz = acc * s + sh;
  zl[(size_t)row * C_ + c] = ln_val(tz, lnzg[c], lnzb[c]);
}

// ------------- fused qv (both branches) + k projection --------------------
__global__ void k_qvk(const float* __restrict__ lnb, const float* __restrict__ zl,
                      const float* __restrict__ qvw, const float* __restrict__ qvb,
                      const float* __restrict__ kw, const float* __restrict__ kb,
                      float* __restrict__ qb, float* __restrict__ vb,
                      float* __restrict__ kk) {
  int z = blockIdx.z;
  if (z < 2) {
    int idx = blockIdx.x * 256 + threadIdx.x;   // B*N*128
    int j = idx & 127;
    int row = idx >> 7;
    int b = row / N_, n = row % N_;
    const float4* ir = (const float4*)(lnb + z * S_ + (size_t)row * C_);
    const float4* wr = (const float4*)(qvw + (size_t)j * C_);
    float acc = qvb[j];
#pragma unroll
    for (int t = 0; t < 16; ++t) {
      float4 a = ir[t], wv = wr[t];
      acc += a.x * wv.x + a.y * wv.y + a.z * wv.z + a.w * wv.w;
    }
    int jj = j & 63;
    int h = jj >> 3, d = jj & 7;
    float* dst = ((j < C_) ? qb : vb) + z * 2 * S_;
    dst[((size_t)(b * NH_ + h) * N_ + n) * HD_ + d] = acc;
  } else {
    if (blockIdx.x >= 1152) return;
    int idx = blockIdx.x * 256 + threadIdx.x;   // B*N*64
    int j = idx & 63;
    int row = idx >> 6;
    int b = row / N_, n = row % N_;
    const float4* ir = (const float4*)(zl + (size_t)row * C_);
    const float4* wr = (const float4*)(kw + (size_t)j * C_);
    float acc = kb[j];
#pragma unroll
    for (int t = 0; t < 16; ++t) {
      float4 a = ir[t], wv = wr[t];
      acc += a.x * wv.x + a.y * wv.y + a.z * wv.z + a.w * wv.w;
    }
    int h = j >> 3, d = j & 7;
    kk[((size_t)(b * NH_ + h) * N_ + n) * HD_ + d] = acc;
  }
}

// ---------------- attention v7: 16 waves, no-max, 2-key ILP ---------------
#define AW 16
__global__ __launch_bounds__(1024, 8) void k_attn7(
    const float* __restrict__ xq, const float* __restrict__ xv,
    const float* __restrict__ yq, const float* __restrict__ yv,
    const float* __restrict__ kk,
    float* __restrict__ outx, float* __restrict__ outy) {
  __shared__ float pl[AW][64];
  __shared__ float pbuf[AW][8][64];
  int bh  = blockIdx.y;
  int qt  = blockIdx.x;
  int tid = threadIdx.x;
  int lane = tid & 63;
  int wave = __builtin_amdgcn_readfirstlane(tid >> 6);
  int q = qt * 64 + lane;
  size_t base = (size_t)bh * N_ * HD_;

  float4 qx0 = ((const float4*)(xq + base + (size_t)q * HD_))[0];
  float4 qx1 = ((const float4*)(xq + base + (size_t)q * HD_))[1];
  float4 qy0 = ((const float4*)(yq + base + (size_t)q * HD_))[0];
  float4 qy1 = ((const float4*)(yq + base + (size_t)q * HD_))[1];
  const float fs = S2_ * LOG2E_;
  qx0.x *= fs; qx0.y *= fs; qx0.z *= fs; qx0.w *= fs;
  qx1.x *= fs; qx1.y *= fs; qx1.z *= fs; qx1.w *= fs;

  float l = 0.f;
  float ax[8] = {0,0,0,0,0,0,0,0};
  float ay[8] = {0,0,0,0,0,0,0,0};

  const float4* kp = (const float4*)(kk + base);
  const float4* xp = (const float4*)(xv + base);
  const float4* yp = (const float4*)(yv + base);
  int k0 = wave * (N_ / AW);
  for (int mi = k0; mi < k0 + N_ / AW; mi += 2) {
    float4 kaA  = kp[2 * mi],     kbA = kp[2 * mi + 1];
    float4 kaB  = kp[2 * mi + 2], kbB = kp[2 * mi + 3];
    float4 xaA = xp[2 * mi],     xbA = xp[2 * mi + 1];
    float4 xaB = xp[2 * mi + 2], xbB = xp[2 * mi + 3];
    float4 yaA = yp[2 * mi],     ybA = yp[2 * mi + 1];
    float4 yaB = yp[2 * mi + 2], ybB = yp[2 * mi + 3];
    float s1A = qx0.x*kaA.x + qx0.y*kaA.y + qx0.z*kaA.z + qx0.w*kaA.w
              + qx1.x*kbA.x + qx1.y*kbA.y + qx1.z*kbA.z + qx1.w*kbA.w;
    float s2A = qy0.x*kaA.x + qy0.y*kaA.y + qy0.z*kaA.z + qy0.w*kaA.w
              + qy1.x*kbA.x + qy1.y*kbA.y + qy1.z*kbA.z + qy1.w*kbA.w;
    float s1B = qx0.x*kaB.x + qx0.y*kaB.y + qx0.z*kaB.z + qx0.w*kaB.w
              + qx1.x*kbB.x + qx1.y*kbB.y + qx1.z*kbB.z + qx1.w*kbB.w;
    float s2B = qy0.x*kaB.x + qy0.y*kaB.y + qy0.z*kaB.z + qy0.w*kaB.w
              + qy1.x*kbB.x + qy1.y*kbB.y + qy1.z*kbB.z + qy1.w*kbB.w;
    float pA = exp2f(s1A * s2A);
    float pB = exp2f(s1B * s2B);
    l += pA + pB;
    ax[0] += pA*xaA.x + pB*xaB.x;  ax[1] += pA*xaA.y + pB*xaB.y;
    ax[2] += pA*xaA.z + pB*xaB.z;  ax[3] += pA*xaA.w + pB*xaB.w;
    ax[4] += pA*xbA.x + pB*xbB.x;  ax[5] += pA*xbA.y + pB*xbB.y;
    ax[6] += pA*xbA.z + pB*xbB.z;  ax[7] += pA*xbA.w + pB*xbB.w;
    ay[0] += pA*yaA.x + pB*yaB.x;  ay[1] += pA*yaA.y + pB*yaB.y;
    ay[2] += pA*yaA.z + pB*yaB.z;  ay[3] += pA*yaA.w + pB*yaB.w;
    ay[4] += pA*ybA.x + pB*ybB.x;  ay[5] += pA*ybA.y + pB*ybB.y;
    ay[6] += pA*ybA.z + pB*ybB.z;  ay[7] += pA*ybA.w + pB*ybB.w;
  }
  pl[wave][lane] = l;
#pragma unroll
  for (int d = 0; d < 8; ++d) pbuf[wave][d][lane] = ax[d];
  __syncthreads();
  float Linv = 0.f;
  int b = bh / NH_, h = bh % NH_;
  if (tid < 64) {
    float L = 0.f;
#pragma unroll
    for (int w = 0; w < AW; ++w) L += pl[w][lane];
    Linv = 1.f / L;
    float A[8] = {0,0,0,0,0,0,0,0};
#pragma unroll
    for (int w = 0; w < AW; ++w)
#pragma unroll
      for (int d = 0; d < 8; ++d) A[d] += pbuf[w][d][lane];
    float* o = outx + ((size_t)(b * N_ + q)) * C_ + h * HD_;
#pragma unroll
    for (int d = 0; d < 8; ++d) o[d] = A[d] * Linv;
  }
  __syncthreads();
#pragma unroll
  for (int d = 0; d < 8; ++d) pbuf[wave][d][lane] = ay[d];
  __syncthreads();
  if (tid < 64) {
    float A[8] = {0,0,0,0,0,0,0,0};
#pragma unroll
    for (int w = 0; w < AW; ++w)
#pragma unroll
      for (int d = 0; d < 8; ++d) A[d] += pbuf[w][d][lane];
    float* o = outy + ((size_t)(b * N_ + q)) * C_ + h * HD_;
#pragma unroll
    for (int d = 0; d < 8; ++d) o[d] = A[d] * Linv;
  }
}

// -------- proj v2: 2 couts + 2 px per thread (att rows shared) ------------
// grid (18, C_/2, 2*B_), block 64. out layout z*CN, z = branch*B_ + b.
__global__ __launch_bounds__(64) void k_proj2(
    const float* __restrict__ attbase,
    const float* __restrict__ x, const float* __restrict__ y,
    const float* bg, const float* bb2, const float* bm, const float* bv,
    const float* __restrict__ pw, const float* __restrict__ pbias,
    float* __restrict__ outbase) {
  int p = blockIdx.x * 128 + threadIdx.x * 2;
  int c0 = blockIdx.y * 2;
  int z = blockIdx.z;
  int branch = z >> 1, b = z & 1;
  const float* att = attbase + branch * S_ + (size_t)b * N_ * C_;
  const float4* w0 = (const float4*)(pw + (size_t)c0 * C_);
  const float4* w1 = (const float4*)(pw + (size_t)(c0 + 1) * C_);
  const float4* ar0 = (const float4*)(att + (size_t)p * C_);
  const float4* ar1 = (const float4*)(att + (size_t)(p + 1) * C_);
  float bias0 = pbias[c0], bias1 = pbias[c0 + 1];
  float a00 = bias0, a01 = bias0, a10 = bias1, a11 = bias1;
#pragma unroll
  for (int t = 0; t < 16; ++t) {
    float4 v0 = ar0[t], v1 = ar1[t];
    float4 u = w0[t], w = w1[t];
    a00 += v0.x*u.x + v0.y*u.y + v0.z*u.z + v0.w*u.w;
    a01 += v1.x*u.x + v1.y*u.y + v1.z*u.z + v1.w*u.w;
    a10 += v0.x*w.x + v0.y*w.y + v0.z*w.z + v0.w*w.w;
    a11 += v1.x*w.x + v1.y*w.y + v1.z*w.z + v1.w*w.w;
  }
  float s0  = bg[c0] * rsqrtf(bv[c0] + EPS_);
  float sh0 = bb2[c0] - bm[c0] * s0;
  float s1  = bg[c0+1] * rsqrtf(bv[c0+1] + EPS_);
  float sh1 = bb2[c0+1] - bm[c0+1] * s1;
  const float* xin = branch ? y : x;
  float2 r0 = *(const float2*)(xin + ((size_t)b * C_ + c0) * N_ + p);
  float2 r1 = *(const float2*)(xin + ((size_t)b * C_ + c0 + 1) * N_ + p);
  size_t o = (size_t)z * CN_ + (size_t)c0 * N_ + p;
  *(float2*)(outbase + o)      = make_float2(a00 + r0.x * s0 + sh0,
                                             a01 + r0.y * s0 + sh0);
  *(float2*)(outbase + o + N_) = make_float2(a10 + r1.x * s1 + sh1,
                                             a11 + r1.y * s1 + sh1);
}

// ------ 64-cin conv RAW partial: cin half, 2 couts + 4 px -----------------
// grid (9, C_/2, 8), block 64. z: img = z&3 (layout img*CN), half = z>>2.
__global__ __launch_bounds__(64) void k_convs(
    const float* __restrict__ inA, const float* __restrict__ inB,
    const float* __restrict__ w,
    float* __restrict__ pA, float* __restrict__ pB) {
  int p = blockIdx.x * 256 + threadIdx.x * 4;
  int c0 = blockIdx.y * 2;
  int z = blockIdx.z;
  int img = z & 3, half = z >> 2;
  int yy = p / W_, x0 = p % W_;      // x0 in {0,4,...,44}; row-contained
  const float* ib = (img < 2) ? inA + (size_t)img * CN_
                              : inB + (size_t)(img - 2) * CN_;
  const float* w0r = w + (size_t)c0 * C_ * 9;
  const float* w1r = w0r + (size_t)C_ * 9;
  float a0 = 0.f, a1 = 0.f, a2 = 0.f, a3 = 0.f;
  float b0 = 0.f, b1 = 0.f, b2 = 0.f, b3 = 0.f;
  int ci0 = half * (C_ / 2);
#pragma unroll 2
  for (int ci = ci0; ci < ci0 + C_ / 2; ++ci) {
    const float* ip = ib + ci * N_;
    const float* wp0 = w0r + ci * 9;
    const float* wp1 = w1r + ci * 9;
#pragma unroll
    for (int ky = 0; ky < 3; ++ky) {
      int iyy = yy + ky - 1;
      if ((unsigned)iyy >= (unsigned)H_) continue;
      const float* rp = ip + iyy * W_;
      float4 mid = *(const float4*)(rp + x0);
      float vL = (x0 > 0) ? rp[x0 - 1] : 0.f;
      float vR = (x0 + 4 < W_) ? rp[x0 + 4] : 0.f;
      float u0 = wp0[ky*3], u1 = wp0[ky*3+1], u2 = wp0[ky*3+2];
      float t0 = wp1[ky*3], t1 = wp1[ky*3+1], t2 = wp1[ky*3+2];
      a0 += vL    * u0 + mid.x * u1 + mid.y * u2;
      a1 += mid.x * u0 + mid.y * u1 + mid.z * u2;
      a2 += mid.y * u0 + mid.z * u1 + mid.w * u2;
      a3 += mid.z * u0 + mid.w * u1 + vR    * u2;
      b0 += vL    * t0 + mid.x * t1 + mid.y * t2;
      b1 += mid.x * t0 + mid.y * t1 + mid.z * t2;
      b2 += mid.y * t0 + mid.z * t1 + mid.w * t2;
      b3 += mid.z * t0 + mid.w * t1 + vR    * t2;
    }
  }
  float* ob = (half ? pB : pA) + (size_t)img * CN_ + (size_t)c0 * N_ + p;
  *(float4*)(ob)      = make_float4(a0, a1, a2, a3);
  *(float4*)(ob + N_) = make_float4(b0, b1, b2, b3);
}

// ------ combine halves + bias + bn + relu (conv1 epilogue) ----------------
__global__ void k_combp(const float* __restrict__ pA, const float* __restrict__ pB,
                        const float* __restrict__ cb,
                        const float* __restrict__ g, const float* __restrict__ b2,
                        const float* __restrict__ m, const float* __restrict__ v,
                        float* __restrict__ tA, float* __restrict__ tB) {
  int t = blockIdx.x * 256 + threadIdx.x;
  int p4 = t * 4;
  int n = p4 % N_;
  int c = (p4 / N_) % C_;
  int img = p4 / (int)CN_;
  size_t off = (size_t)img * CN_ + (size_t)c * N_ + n;
  float4 a = *(const float4*)(pA + off);
  float4 d = *(const float4*)(pB + off);
  float s  = g[c] * rsqrtf(v[c] + EPS_);
  float sh = b2[c] - m[c] * s;
  float bias = cb[c];
  float4 r;
  r.x = fmaxf((a.x + d.x + bias) * s + sh, 0.f);
  r.y = fmaxf((a.y + d.y + bias) * s + sh, 0.f);
  r.z = fmaxf((a.z + d.z + bias) * s + sh, 0.f);
  r.w = fmaxf((a.w + d.w + bias) * s + sh, 0.f);
  float* ob = (img < 2) ? tA + off : tB + off - 2 * CN_;
  *(float4*)ob = r;
}

// ------ combine halves + bias + bn + relu + resid (conv2 epilogue) --------
__global__ void k_comb2(float* __restrict__ pA, const float* __restrict__ pB,
                        const float* __restrict__ cb,
                        const float* __restrict__ g, const float* __restrict__ b2,
                        const float* __restrict__ m, const float* __restrict__ v,
                        const float* __restrict__ resid) {
  int t = blockIdx.x * 256 + threadIdx.x;
  int p4 = t * 4;
  int n = p4 % N_;
  int c = (p4 / N_) % C_;
  int img = p4 / (int)CN_;
  size_t off = (size_t)img * CN_ + (size_t)c * N_ + n;
  float4 a = *(const float4*)(pA + off);
  float4 d = *(const float4*)(pB + off);
  float4 rr = *(const float4*)(resid + off);
  float s  = g[c] * rsqrtf(v[c] + EPS_);
  float sh = b2[c] - m[c] * s;
  float bias = cb[c];
  float4 r;
  r.x = fmaxf((a.x + d.x + bias) * s + sh, 0.f) + rr.x;
  r.y = fmaxf((a.y + d.y + bias) * s + sh, 0.f) + rr.y;
  r.z = fmaxf((a.z + d.z + bias) * s + sh, 0.f) + rr.z;
  r.w = fmaxf((a.w + d.w + bias) * s + sh, 0.f) + rr.w;
  *(float4*)(pA + off) = r;
}

// ------ cat = [xo+yo ; xo*yo] + bn2 -> fin, float4 ------------------------
__global__ void k_catbn(const float* __restrict__ o2,
                        const float* __restrict__ g, const float* __restrict__ b2,
                        const float* __restrict__ m, const float* __restrict__ v,
                        float* __restrict__ cat, float* __restrict__ fin,
                        size_t finStride) {
  int t = blockIdx.x * 256 + threadIdx.x;
  int p4 = t * 4;
  int n  = p4 % N_;
  int c2 = (p4 / N_) % (2 * C_);
  int b  = p4 / (2 * C_ * N_);
  int c  = c2 & 63;
  float4 X = *(const float4*)(o2 + (size_t)b * CN_ + (size_t)c * N_ + n);
  float4 Y = *(const float4*)(o2 + (size_t)(2 + b) * CN_ + (size_t)c * N_ + n);
  float4 val;
  if (c2 < C_) val = make_float4(X.x + Y.x, X.y + Y.y, X.z + Y.z, X.w + Y.w);
  else         val = make_float4(X.x * Y.x, X.y * Y.y, X.z * Y.z, X.w * Y.w);
  size_t co = ((size_t)b * 2 * C_ + c2) * N_ + n;
  *(float4*)(cat + co) = val;
  float s  = g[c2] * rsqrtf(v[c2] + EPS_);
  float sh = b2[c2] - m[c2] * s;
  *(float4*)(fin + (size_t)b * finStride + (size_t)c2 * N_ + n) =
      make_float4(val.x * s + sh, val.y * s + sh, val.z * s + sh, val.w * s + sh);
}

// ------ f-branch 3x3 conv partial (64-cin half), 2 couts + 4 px -----------
// grid (9, C_, 2*B_), block 64. z: b = z&1, half = z>>1.
__global__ __launch_bounds__(64) void k_fconvs(
    const float* __restrict__ in, size_t inStride,
    const float* __restrict__ w,
    float* __restrict__ outA, size_t outStrideA,
    float* __restrict__ outB, size_t outStrideB) {
  int p = blockIdx.x * 256 + threadIdx.x * 4;
  int c0 = blockIdx.y * 2;
  int z = blockIdx.z;
  int b = z & 1, half = z >> 1;
  int yy = p / W_, x0 = p % W_;
  const float* ib = in + (size_t)b * inStride;
  const float* w0r = w + (size_t)c0 * (2 * C_) * 9;
  const float* w1r = w0r + (size_t)(2 * C_) * 9;
  float a0 = 0.f, a1 = 0.f, a2 = 0.f, a3 = 0.f;
  float b0 = 0.f, b1 = 0.f, b2 = 0.f, b3 = 0.f;
  int ci0 = half * C_;
#pragma unroll 2
  for (int ci = ci0; ci < ci0 + C_; ++ci) {
    const float* ip = ib + ci * N_;
    const float* wp0 = w0r + ci * 9;
    const float* wp1 = w1r + ci * 9;
#pragma unroll
    for (int ky = 0; ky < 3; ++ky) {
      int iyy = yy + ky - 1;
      if ((unsigned)iyy >= (unsigned)H_) continue;
      const float* rp = ip + iyy * W_;
      float4 mid = *(const float4*)(rp + x0);
      float vL = (x0 > 0) ? rp[x0 - 1] : 0.f;
      float vR = (x0 + 4 < W_) ? rp[x0 + 4] : 0.f;
      float u0 = wp0[ky*3], u1 = wp0[ky*3+1], u2 = wp0[ky*3+2];
      float t0 = wp1[ky*3], t1 = wp1[ky*3+1], t2 = wp1[ky*3+2];
      a0 += vL    * u0 + mid.x * u1 + mid.y * u2;
      a1 += mid.x * u0 + mid.y * u1 + mid.z * u2;
      a2 += mid.y * u0 + mid.z * u1 + mid.w * u2;
      a3 += mid.z * u0 + mid.w * u1 + vR    * u2;
      b0 += vL    * t0 + mid.x * t1 + mid.y * t2;
      b1 += mid.x * t0 + mid.y * t1 + mid.z * t2;
      b2 += mid.y * t0 + mid.z * t1 + mid.w * t2;
      b3 += mid.z * t0 + mid.w * t1 + vR    * t2;
    }
  }
  float* ob = (half ? outB + (size_t)b * outStrideB
                    : outA + (size_t)b * outStrideA);
  size_t o = (size_t)c0 * N_ + p;
  *(float4*)(ob + o)      = make_float4(a0, a1, a2, a3);
  *(float4*)(ob + o + N_) = make_float4(b0, b1, b2, b3);
}

// ------ combine halves + bn + relu, float4 (in-place into A ok) -----------
__global__ void k_comb(const float* __restrict__ pA, size_t strideA,
                       const float* __restrict__ pB, size_t strideB,
                       const float* __restrict__ g, const float* __restrict__ b2,
                       const float* __restrict__ m, const float* __restrict__ v,
                       float* __restrict__ out, size_t outStride) {
  int t = blockIdx.x * 256 + threadIdx.x;
  int p4 = t * 4;
  int n = p4 % N_;
  int c = (p4 / N_) % (2 * C_);
  int b = p4 / (2 * C_ * N_);
  size_t off = (size_t)c * N_ + n;
  float4 a = *(const float4*)(pA + (size_t)b * strideA + off);
  float4 d = *(const float4*)(pB + (size_t)b * strideB + off);
  float s  = g[c] * rsqrtf(v[c] + EPS_);
  float sh = b2[c] - m[c] * s;
  float4 r;
  r.x = fmaxf((a.x + d.x) * s + sh, 0.f);
  r.y = fmaxf((a.y + d.y) * s + sh, 0.f);
  r.z = fmaxf((a.z + d.z) * s + sh, 0.f);
  r.w = fmaxf((a.w + d.w) * s + sh, 0.f);
  *(float4*)(out + (size_t)b * outStride + off) = r;
}

// -------- final v2: 2 couts/block, fused comb(fbn2)+relu + cat add --------
// grid (18, C_, B_), block 64. bn scale/shift precomputed into LDS.
__global__ __launch_bounds__(64) void k_final3(
    const float* __restrict__ pA, size_t strideA,
    const float* __restrict__ pB, size_t strideB,
    const float* __restrict__ g2, const float* __restrict__ b2,
    const float* __restrict__ m2, const float* __restrict__ v2,
    const float* __restrict__ cat,
    const float* __restrict__ w, const float* __restrict__ fb,
    float* __restrict__ out) {
  __shared__ float fsc[2 * C_], fsh[2 * C_];
  for (int j = threadIdx.x; j < 2 * C_; j += 64) {
    float s = g2[j] * rsqrtf(v2[j] + EPS_);
    fsc[j] = s;
    fsh[j] = b2[j] - m2[j] * s;
  }
  __syncthreads();
  int p = blockIdx.x * 128 + threadIdx.x * 2;
  int c0 = blockIdx.y * 2;
  int b = blockIdx.z;
  const float* frA = pA + (size_t)b * strideA;
  const float* frB = pB + (size_t)b * strideB;
  const float* wr0 = w + (size_t)c0 * 2 * C_;
  const float* wr1 = wr0 + 2 * C_;
  float a00 = fb[c0], a01 = a00;
  float a10 = fb[c0 + 1], a11 = a10;
#pragma unroll 4
  for (int j = 0; j < 2 * C_; ++j) {
    float2 fa = *(const float2*)(frA + (size_t)j * N_ + p);
    float2 fd = *(const float2*)(frB + (size_t)j * N_ + p);
    float s = fsc[j], sh = fsh[j];
    float f0 = fmaxf((fa.x + fd.x) * s + sh, 0.f);
    float f1 = fmaxf((fa.y + fd.y) * s + sh, 0.f);
    float wv0 = wr0[j], wv1 = wr1[j];
    a00 += wv0 * f0; a01 += wv0 * f1;
    a10 += wv1 * f0; a11 += wv1 * f1;
  }
  size_t o = ((size_t)b * 2 * C_ + c0) * N_ + p;
  float2 cv0 = *(const float2*)(cat + o);
  float2 cv1 = *(const float2*)(cat + o + N_);
  *(float2*)(out + o)      = make_float2(a00 + cv0.x, a01 + cv0.y);
  *(float2*)(out + o + N_) = make_float2(a10 + cv1.x, a11 + cv1.y);
}

extern "C" void kernel_launch(void* const* d_in, const int* in_sizes, int n_in,
                              void* d_out, int out_size, void* d_ws, size_t ws_size,
                              hipStream_t stream) {
  const float* x       = (const float*)d_in[0];
  const float* y       = (const float*)d_in[1];
  const float* pconv_w = (const float*)d_in[2];
  const float* pconv_b = (const float*)d_in[3];
  const float* bnd_g = (const float*)d_in[4];
  const float* bnd_b = (const float*)d_in[5];
  const float* bnd_m = (const float*)d_in[6];
  const float* bnd_v = (const float*)d_in[7];
  const float* lnx_g = (const float*)d_in[8];
  const float* lnx_b = (const float*)d_in[9];
  const float* lny_g = (const float*)d_in[10];
  const float* lny_b = (const float*)d_in[11];
  const float* lnz_g = (const float*)d_in[12];
  const float* lnz_b = (const float*)d_in[13];
  const float* k_w   = (const float*)d_in[14];
  const float* k_b   = (const float*)d_in[15];
  const float* qv_w  = (const float*)d_in[16];
  const float* qv_b  = (const float*)d_in[17];
  const float* proj_w = (const float*)d_in[18];
  const float* proj_b = (const float*)d_in[19];
  const float* c2w1  = (const float*)d_in[20];
  const float* c2b1  = (const float*)d_in[21];
  const float* c2bn1_g = (const float*)d_in[22];
  const float* c2bn1_b = (const float*)d_in[23];
  const float* c2bn1_m = (const float*)d_in[24];
  const float* c2bn1_v = (const float*)d_in[25];
  const float* c2w2  = (const float*)d_in[26];
  const float* c2b2  = (const float*)d_in[27];
  const float* c2bn2_g = (const float*)d_in[28];
  const float* c2bn2_b = (const float*)d_in[29];
  const float* c2bn2_m = (const float*)d_in[30];
  const float* c2bn2_v = (const float*)d_in[31];
  const float* bn2_g = (const float*)d_in[32];
  const float* bn2_b = (const float*)d_in[33];
  const float* bn2_m = (const float*)d_in[34];
  const float* bn2_v = (const float*)d_in[35];
  const float* f1w   = (const float*)d_in[36];
  const float* fbn1_g = (const float*)d_in[37];
  const float* fbn1_b = (const float*)d_in[38];
  const float* fbn1_m = (const float*)d_in[39];
  const float* fbn1_v = (const float*)d_in[40];
  const float* f2w   = (const float*)d_in[41];
  const float* fbn2_g = (const float*)d_in[42];
  const float* fbn2_b = (const float*)d_in[43];
  const float* fbn2_m = (const float*)d_in[44];
  const float* fbn2_v = (const float*)d_in[45];
  const float* f3w   = (const float*)d_in[46];
  const float* f3b   = (const float*)d_in[47];

  // 8-slot workspace plan (same as R15-R17):
  //   A: k_pre -> xl(1) yl(2) zl(3)
  //   B: qvk -> xq(4) xv(5) yq(6) yv(7); kk(0)
  //   C: attn7 -> att_xo(1) att_yo(2)
  //   D: proj -> xo4(3,4) [img*CN, imgs 0..3]
  //   E1: convs(conv1) raw partials: half0 -> (1,2), half1 -> (5,6)
  //   E2: combp (+bias/bn/relu) -> tmp imgs01 (0), imgs23 (7)
  //   F1: convs(conv2) raw partials from tmp -> (1,2)(5,6)
  //   F2: comb2 (+bias/bn/relu + resid(3,4)) -> o2 in-place (1,2)
  //   G: catbn reads o2(1,2) -> cat(3,4), fin b0->(0), b1->(7) [stride 7S]
  //   H1: fconvs f1: fin(0/7) -> half0 (1,2 stride S), half1 (5,6 stride S)
  //   H2: comb -> (1,2) in-place
  //   H3: fconvs f2: (1,2) -> half0 (5,6), half1 (0/7)
  //   I: final3 reads (5,6)+(0/7), cat(3,4) -> out
  float* ws = (float*)d_ws;
  float* sl0 = ws + 0 * S_;
  float* sl1 = ws + 1 * S_;
  float* sl2 = ws + 2 * S_;
  float* sl3 = ws + 3 * S_;
  float* sl4 = ws + 4 * S_;
  float* sl5 = ws + 5 * S_;
  float* sl7 = ws + 7 * S_;

  // A. fused pconv + bn + ln
  k_pre<<<B_ * N_, 64, 0, stream>>>(x, y, pconv_w, pconv_b,
                                    bnd_g, bnd_b, bnd_m, bnd_v,
                                    lnx_g, lnx_b, lny_g, lny_b, lnz_g, lnz_b,
                                    sl1, sl2, sl3);
  // B. fused qv + kproj
  {
    dim3 g(2304, 1, 3);
    k_qvk<<<g, 256, 0, stream>>>(sl1, sl3, qv_w, qv_b, k_w, k_b, sl4, sl5, sl0);
  }
  // C. attention v7 -> att_xo(1), att_yo(2)
  {
    dim3 g(N_ / 64, B_ * NH_);
    k_attn7<<<g, 1024, 0, stream>>>(sl4, sl5, ws + 6 * S_, ws + 7 * S_, sl0,
                                    sl1, sl2);
  }
  // D. proj v2 (2 couts) -> xo4(3,4)
  {
    dim3 g(18, C_ / 2, 2 * B_);
    k_proj2<<<g, 64, 0, stream>>>(sl1, x, y, bnd_g, bnd_b, bnd_m, bnd_v,
                                  proj_w, proj_b, sl3);
  }
  // E. conv1: cin-split raw partials (4 px) + combine epilogue -> tmp(0 / 7)
  {
    dim3 g(9, C_ / 2, 8);
    k_convs<<<g, 64, 0, stream>>>(sl3, sl3 + 2 * CN_, c2w1, sl1, sl5);
    k_combp<<<576, 256, 0, stream>>>(sl1, sl5, c2b1,
        c2bn1_g, c2bn1_b, c2bn1_m, c2bn1_v, sl0, sl7);
  }
  // F. conv2: cin-split raw partials (4 px) + combine(+resid) -> o2(1,2)
  {
    dim3 g(9, C_ / 2, 8);
    k_convs<<<g, 64, 0, stream>>>(sl0, sl7, c2w2, sl1, sl5);
    k_comb2<<<576, 256, 0, stream>>>(sl1, sl5, c2b2,
        c2bn2_g, c2bn2_b, c2bn2_m, c2bn2_v, sl3);
  }
  // G. cat + bn2 -> cat(3,4), fin(0 / 7)
  k_catbn<<<576, 256, 0, stream>>>(sl1, bn2_g, bn2_b, bn2_m, bn2_v,
                                   sl3, sl0, 7 * S_);
  // H. f-branch convs, ci-split, 4 px/thread
  {
    dim3 g(9, C_, 2 * B_);
    k_fconvs<<<g, 64, 0, stream>>>(sl0, 7 * S_, f1w, sl1, S_, sl5, S_);
    k_comb<<<576, 256, 0, stream>>>(sl1, S_, sl5, S_,
                                    fbn1_g, fbn1_b, fbn1_m, fbn1_v, sl1, S_);
    k_fconvs<<<g, 64, 0, stream>>>(sl1, S_, f2w, sl5, S_, sl0, 7 * S_);
  }
  // I. final v2 (2 couts) -> fp32 out
  {
    dim3 g(18, C_, B_);
    k_final3<<<g, 64, 0, stream>>>(sl5, S_, sl0, 7 * S_,
                                   fbn2_g, fbn2_b, fbn2_m, fbn2_v,
                                   sl3, f3w, f3b, (float*)d_out);
  }
}